// Round 9
// baseline (249.675 us; speedup 1.0000x reference)
//
#include <hip/hip_runtime.h>
#include <math.h>

using bf16x8 = __attribute__((ext_vector_type(8))) short;
using f32x4  = __attribute__((ext_vector_type(4))) float;

struct __align__(8) us4 { unsigned short x, y, z, w; };
struct __align__(8) u32x2 { unsigned int x, y; };

__device__ __forceinline__ unsigned short f2b(float f) {
  union { float f; unsigned u; } v; v.f = f;
  unsigned r = v.u + 0x7FFFu + ((v.u >> 16) & 1u);
  return (unsigned short)(r >> 16);
}
__device__ __forceinline__ unsigned int cvt_pk_bf16(float lo, float hi) {
  unsigned int d;
  asm("v_cvt_pk_bf16_f32 %0, %1, %2" : "=v"(d) : "v"(lo), "v"(hi));
  return d;
}

#define GLDS(g, l) __builtin_amdgcn_global_load_lds(                        \
    (const __attribute__((address_space(1))) void*)(g),                    \
    (__attribute__((address_space(3))) void*)(l), 16, 0, 0)

// ---------------------------------------------------------------------------
// Fused prep: LN1 (blocks 0..4095) + all 6 weight transposes (fp32->bf16,
// [K][N] -> [N][K]) in one dispatch. All parts independent; removes 6 small
// serialized dispatches from the critical path.
// ---------------------------------------------------------------------------
__global__ void __launch_bounds__(256) prep_kernel(
    const float* __restrict__ hs, const float* __restrict__ ln1s,
    const float* __restrict__ ln1b, unsigned short* __restrict__ xb,
    const float* __restrict__ Wq, const float* __restrict__ Wk,
    const float* __restrict__ Wv, const float* __restrict__ Wo,
    const float* __restrict__ W1, const float* __restrict__ W2,
    unsigned short* __restrict__ wqkvT, unsigned short* __restrict__ woT,
    unsigned short* __restrict__ w1T, unsigned short* __restrict__ w2T) {
  const int id = blockIdx.x;
  const int t = threadIdx.x;
  __shared__ float tile[32][33];
  __shared__ float red[8];

  if (id < 4096) {  // ---- LN1 row ----
    const int row = id;
    const float4 v = ((const float4*)(hs + (size_t)row * 1024))[t];
    float s  = v.x + v.y + v.z + v.w;
    float s2 = v.x * v.x + v.y * v.y + v.z * v.z + v.w * v.w;
#pragma unroll
    for (int off = 32; off; off >>= 1) {
      s  += __shfl_xor(s,  off);
      s2 += __shfl_xor(s2, off);
    }
    const int w = t >> 6, lane = t & 63;
    if (!lane) { red[w] = s; red[4 + w] = s2; }
    __syncthreads();
    s  = red[0] + red[1] + red[2] + red[3];
    s2 = red[4] + red[5] + red[6] + red[7];
    const float mean = s * (1.0f / 1024.0f);
    const float var  = s2 * (1.0f / 1024.0f) - mean * mean;
    const float rstd = rsqrtf(var + 1e-5f);
    const float4 sc = ((const float4*)ln1s)[t];
    const float4 sh = ((const float4*)ln1b)[t];
    us4 o;
    o.x = f2b((v.x - mean) * rstd * sc.x + sh.x);
    o.y = f2b((v.y - mean) * rstd * sc.y + sh.y);
    o.z = f2b((v.z - mean) * rstd * sc.z + sh.z);
    o.w = f2b((v.w - mean) * rstd * sc.w + sh.w);
    ((us4*)(xb + (size_t)row * 1024))[t] = o;
    return;
  }

  // ---- weight transpose tile ----
  const float* src; unsigned short* dst; int K, N, n0, k0;
  if (id < 8192) {            // Wq/Wk/Wv/Wo: 1024x1024, 32x32 grids
    const int which = (id - 4096) >> 10, local = (id - 4096) & 1023;
    src = (which == 0) ? Wq : (which == 1) ? Wk : (which == 2) ? Wv : Wo;
    dst = (which == 3) ? woT : wqkvT + (size_t)which * 1048576;
    K = 1024; N = 1024;
    n0 = (local & 31) * 32; k0 = (local >> 5) * 32;
  } else if (id < 12288) {    // W1: K=1024, N=4096, grid (128,32)
    const int local = id - 8192;
    src = W1; dst = w1T; K = 1024; N = 4096;
    n0 = (local & 127) * 32; k0 = (local >> 7) * 32;
  } else {                    // W2: K=4096, N=1024, grid (32,128)
    const int local = id - 12288;
    src = W2; dst = w2T; K = 4096; N = 1024;
    n0 = (local & 31) * 32; k0 = (local >> 5) * 32;
  }
  const int tx = t & 31, ty = t >> 5;  // 32 x 8
#pragma unroll
  for (int i = 0; i < 32; i += 8)
    tile[ty + i][tx] = src[(size_t)(k0 + ty + i) * N + n0 + tx];
  __syncthreads();
#pragma unroll
  for (int i = 0; i < 32; i += 8)
    dst[(size_t)(n0 + ty + i) * K + k0 + tx] = f2b(tile[tx][ty + i]);
}

// ---------------------------------------------------------------------------
// LayerNorm over last dim (1024), fp32 in -> bf16 out (LN2)
// ---------------------------------------------------------------------------
__global__ void __launch_bounds__(256) ln_kernel(
    const float* __restrict__ in, const float* __restrict__ scale,
    const float* __restrict__ shift, unsigned short* __restrict__ out) {
  const int row = blockIdx.x, t = threadIdx.x;
  const float4 v = ((const float4*)(in + (size_t)row * 1024))[t];
  float s  = v.x + v.y + v.z + v.w;
  float s2 = v.x * v.x + v.y * v.y + v.z * v.z + v.w * v.w;
#pragma unroll
  for (int off = 32; off; off >>= 1) {
    s  += __shfl_xor(s,  off);
    s2 += __shfl_xor(s2, off);
  }
  __shared__ float red[8];
  const int w = t >> 6, lane = t & 63;
  if (!lane) { red[w] = s; red[4 + w] = s2; }
  __syncthreads();
  s  = red[0] + red[1] + red[2] + red[3];
  s2 = red[4] + red[5] + red[6] + red[7];
  const float mean = s * (1.0f / 1024.0f);
  const float var  = s2 * (1.0f / 1024.0f) - mean * mean;
  const float rstd = rsqrtf(var + 1e-5f);
  const float4 sc = ((const float4*)scale)[t];
  const float4 sh = ((const float4*)shift)[t];
  us4 o;
  o.x = f2b((v.x - mean) * rstd * sc.x + sh.x);
  o.y = f2b((v.y - mean) * rstd * sc.y + sh.y);
  o.z = f2b((v.z - mean) * rstd * sc.z + sh.z);
  o.w = f2b((v.w - mean) * rstd * sc.w + sh.w);
  ((us4*)(out + (size_t)row * 1024))[t] = o;
}

// ---------------------------------------------------------------------------
// 256x256 GEMM, 8 waves (2M x 4N), BK=64, counted-vmcnt pipeline (round-6
// version — best measured). MODE 0: qkv split -> qk + vt (V^T).
// MODE 2: out_bf16 = gelu_tanh(acc + bias)
// ---------------------------------------------------------------------------
template <int MODE>
__global__ void __launch_bounds__(512, 2) gemm256(
    const unsigned short* __restrict__ A, const unsigned short* __restrict__ B,
    int K, int N, unsigned short* __restrict__ outb,
    const float* __restrict__ bias, unsigned short* __restrict__ vt) {
  __shared__ unsigned short lA[2][256 * 64];
  __shared__ unsigned short lB[2][256 * 64];
  const int t = threadIdx.x, lane = t & 63;
  const int w = t >> 6, wm = w >> 2, wn = w & 3;
  const int r16 = lane & 15, g = lane >> 4;
  const int m0 = blockIdx.x * 256, n0 = blockIdx.y * 256;

  const unsigned short* aSrc[4];
  const unsigned short* bSrc[4];
#pragma unroll
  for (int p = 0; p < 4; ++p) {
    const int ci = t + p * 512, r = ci >> 3, cs = ci & 7;
    aSrc[p] = A + (size_t)(m0 + r) * K + (cs ^ (r & 7)) * 8;
    bSrc[p] = B + (size_t)(n0 + r) * K + (cs ^ (r & 7)) * 8;
  }
  int aOff[8][2], bOff[4][2];
#pragma unroll
  for (int i = 0; i < 8; ++i)
#pragma unroll
    for (int ks = 0; ks < 2; ++ks) {
      const int m = wm * 128 + i * 16 + r16, kb = ks * 4 + g;
      aOff[i][ks] = ((m << 3) + (kb ^ (m & 7))) << 3;
    }
#pragma unroll
  for (int j = 0; j < 4; ++j)
#pragma unroll
    for (int ks = 0; ks < 2; ++ks) {
      const int n = wn * 64 + j * 16 + r16, kb = ks * 4 + g;
      bOff[j][ks] = ((n << 3) + (kb ^ (n & 7))) << 3;
    }

  auto stage = [&](int buf, int kt) {
    const int off = kt * 64;
#pragma unroll
    for (int p = 0; p < 4; ++p) {
      GLDS(aSrc[p] + off, &lA[buf][(t + p * 512) * 8]);
      GLDS(bSrc[p] + off, &lB[buf][(t + p * 512) * 8]);
    }
  };

  f32x4 acc[8][4] = {};
  const int nkt = K >> 6;
  stage(0, 0);
  for (int kt = 0; kt < nkt; ++kt) {
    const int cur = kt & 1;
    if (kt + 1 < nkt) {
      stage(cur ^ 1, kt + 1);  // 8 loads into buf[cur^1], left in flight
      asm volatile("s_waitcnt vmcnt(8)" ::: "memory");  // buf[cur] landed
    } else {
      asm volatile("s_waitcnt vmcnt(0)" ::: "memory");
    }
    __builtin_amdgcn_s_barrier();          // all waves: buf[cur] staged
    __builtin_amdgcn_sched_barrier(0);     // no LDS reads hoisted above
    const unsigned short* bA = lA[cur];
    const unsigned short* bB = lB[cur];
#pragma unroll
    for (int ks = 0; ks < 2; ++ks) {
      bf16x8 af[8], bfr[4];
#pragma unroll
      for (int i = 0; i < 8; ++i) af[i] = *(const bf16x8*)&bA[aOff[i][ks]];
#pragma unroll
      for (int j = 0; j < 4; ++j) bfr[j] = *(const bf16x8*)&bB[bOff[j][ks]];
      __builtin_amdgcn_s_setprio(1);
#pragma unroll
      for (int i = 0; i < 8; ++i)
#pragma unroll
        for (int j = 0; j < 4; ++j)
          acc[i][j] = __builtin_amdgcn_mfma_f32_16x16x32_bf16(
              af[i], bfr[j], acc[i][j], 0, 0, 0);
      __builtin_amdgcn_s_setprio(0);
    }
    __builtin_amdgcn_sched_barrier(0);     // no next-iter GLDS hoisted above
    __builtin_amdgcn_s_barrier();          // all waves done reading buf[cur]
  }

  float bj[4];
  if constexpr (MODE == 2) {
#pragma unroll
    for (int j = 0; j < 4; ++j) bj[j] = bias[n0 + wn * 64 + j * 16 + r16];
  }
#pragma unroll
  for (int i = 0; i < 8; ++i) {
    const int row0 = m0 + wm * 128 + i * 16 + g * 4;
#pragma unroll
    for (int j = 0; j < 4; ++j) {
      const int colb = n0 + wn * 64 + j * 16;
      const int col = colb + r16;
      if constexpr (MODE == 0) {
        if (colb < 2048) {
#pragma unroll
          for (int r = 0; r < 4; ++r)
            outb[(size_t)(row0 + r) * 2048 + col] = f2b(acc[i][j][r]);
        } else {
          const int b = row0 >> 11, s0 = row0 & 2047;
          us4 pk;
          pk.x = f2b(acc[i][j][0]); pk.y = f2b(acc[i][j][1]);
          pk.z = f2b(acc[i][j][2]); pk.w = f2b(acc[i][j][3]);
          *(us4*)&vt[((size_t)b * 1024 + (col - 2048)) * 2048 + s0] = pk;
        }
      } else {
#pragma unroll
        for (int r = 0; r < 4; ++r) {
          const float x = acc[i][j][r] + bj[j];
          const float u = x * (0.7978845608028654f + 0.03567740814f * x * x);
          const float e = __builtin_amdgcn_exp2f(u * 2.885390081777927f);
          const float th = 1.0f - 2.0f * __builtin_amdgcn_rcpf(e + 1.0f);
          outb[(size_t)(row0 + r) * N + col] = f2b(0.5f * x * (1.0f + th));
        }
      }
    }
  }
}

// ---------------------------------------------------------------------------
// GEMM: C[M,N] = A[M,K](bf16) * B^T, B stored [N,K]. BMx128 tile, 4 waves.
// 2-deep counted-vmcnt pipeline (round-6 version). N=1024 GEMMs (Wo, FFN-dn).
// MODE 1: out_f32 = acc + resid ; MODE 3: out_f32 = acc + bias + resid
// ---------------------------------------------------------------------------
template <int MODE, int BM>
__global__ void __launch_bounds__(256) gemm_bt(
    const unsigned short* __restrict__ A, const unsigned short* __restrict__ B,
    int K, int N,
    float* __restrict__ outf, const float* __restrict__ bias,
    const float* __restrict__ resid) {
  constexpr int WN = (BM == 128) ? 2 : 4;   // waves along N
  constexpr int NJ = 128 / (16 * WN);       // N-fragments per wave
  constexpr int ACH = BM / 32;              // A staging passes
  __shared__ unsigned short lA[2][BM * 64];
  __shared__ unsigned short lB[2][128 * 64];
  const int t = threadIdx.x, lane = t & 63;
  const int w = t >> 6, wm = w / WN, wn = w % WN;
  const int r16 = lane & 15, g = lane >> 4;
  const int m0 = blockIdx.x * BM, n0 = blockIdx.y * 128;

  const unsigned short* aSrc[ACH];
  const unsigned short* bSrc[4];
#pragma unroll
  for (int p = 0; p < ACH; ++p) {
    const int ci = t + p * 256, m = ci >> 3, cs = ci & 7;
    aSrc[p] = A + (size_t)(m0 + m) * K + (cs ^ (m & 7)) * 8;
  }
#pragma unroll
  for (int p = 0; p < 4; ++p) {
    const int ci = t + p * 256, m = ci >> 3, cs = ci & 7;
    bSrc[p] = B + (size_t)(n0 + m) * K + (cs ^ (m & 7)) * 8;
  }

  int aOff[4][2], bOff[NJ][2];
#pragma unroll
  for (int i = 0; i < 4; ++i)
#pragma unroll
    for (int ks = 0; ks < 2; ++ks) {
      const int m = wm * 64 + i * 16 + r16, kb = ks * 4 + g;
      aOff[i][ks] = ((m << 3) + (kb ^ (m & 7))) << 3;
    }
#pragma unroll
  for (int j = 0; j < NJ; ++j)
#pragma unroll
    for (int ks = 0; ks < 2; ++ks) {
      const int n = wn * (16 * NJ) + j * 16 + r16, kb = ks * 4 + g;
      bOff[j][ks] = ((n << 3) + (kb ^ (n & 7))) << 3;
    }

  auto stage = [&](int buf, int kt) {
    const int off = kt * 64;
#pragma unroll
    for (int p = 0; p < ACH; ++p)
      GLDS(aSrc[p] + off, &lA[buf][(t + p * 256) * 8]);
#pragma unroll
    for (int p = 0; p < 4; ++p)
      GLDS(bSrc[p] + off, &lB[buf][(t + p * 256) * 8]);
  };

  f32x4 acc[4][NJ] = {};
  const int nkt = K >> 6;
  stage(0, 0);
  for (int kt = 0; kt < nkt; ++kt) {
    const int cur = kt & 1;
    if (kt + 1 < nkt) {
      stage(cur ^ 1, kt + 1);  // 6 loads into buf[cur^1], left in flight
      if constexpr (ACH == 2)
        asm volatile("s_waitcnt vmcnt(6)" ::: "memory");  // buf[cur] landed
      else
        asm volatile("s_waitcnt vmcnt(8)" ::: "memory");
    } else {
      asm volatile("s_waitcnt vmcnt(0)" ::: "memory");
    }
    __builtin_amdgcn_s_barrier();          // all waves: buf[cur] staged
    __builtin_amdgcn_sched_barrier(0);     // no LDS reads hoisted above
    const unsigned short* bA = lA[cur];
    const unsigned short* bB = lB[cur];
#pragma unroll
    for (int ks = 0; ks < 2; ++ks) {
      bf16x8 af[4], bfr[NJ];
#pragma unroll
      for (int i = 0; i < 4; ++i) af[i] = *(const bf16x8*)&bA[aOff[i][ks]];
#pragma unroll
      for (int j = 0; j < NJ; ++j) bfr[j] = *(const bf16x8*)&bB[bOff[j][ks]];
      __builtin_amdgcn_s_setprio(1);
#pragma unroll
      for (int i = 0; i < 4; ++i)
#pragma unroll
        for (int j = 0; j < NJ; ++j)
          acc[i][j] = __builtin_amdgcn_mfma_f32_16x16x32_bf16(
              af[i], bfr[j], acc[i][j], 0, 0, 0);
      __builtin_amdgcn_s_setprio(0);
    }
    __builtin_amdgcn_sched_barrier(0);     // no next-iter GLDS hoisted above
    __builtin_amdgcn_s_barrier();          // all waves done reading buf[cur]
  }

  float bj[NJ];
  if constexpr (MODE == 3) {
#pragma unroll
    for (int j = 0; j < NJ; ++j)
      bj[j] = bias[n0 + wn * (16 * NJ) + j * 16 + r16];
  }
#pragma unroll
  for (int i = 0; i < 4; ++i) {
    const int row0 = m0 + wm * 64 + i * 16 + g * 4;
#pragma unroll
    for (int j = 0; j < NJ; ++j) {
      const int col = n0 + wn * (16 * NJ) + j * 16 + r16;
      if constexpr (MODE == 1) {
#pragma unroll
        for (int r = 0; r < 4; ++r) {
          const size_t idx = (size_t)(row0 + r) * N + col;
          outf[idx] = acc[i][j][r] + resid[idx];
        }
      } else {
#pragma unroll
        for (int r = 0; r < 4; ++r) {
          const size_t idx = (size_t)(row0 + r) * N + col;
          outf[idx] = acc[i][j][r] + bj[j] + resid[idx];
        }
      }
    }
  }
}

// ---------------------------------------------------------------------------
// Flash attention (causal), KVBLK=128: block j handles q-tiles j and 31-j over
// 128-row K/V tiles -> a UNIFORM 17 barrier-steps per block (was 33), halving
// sync/stage overhead. Grid (16,16,2), 4 waves, 80KB LDS (2 blocks/CU).
// Swapped QK^T; P^T via XOR-swizzled per-wave lP; V pre-transposed vt[b][d][s].
// T5 setprio, T13 defer-max, cvt_pk packing.
// ---------------------------------------------------------------------------
__global__ void __launch_bounds__(256) attn_kernel(
    const unsigned short* __restrict__ qk, const unsigned short* __restrict__ vt,
    unsigned short* __restrict__ obuf) {
  const int j = blockIdx.x, h = blockIdx.y, bb = blockIdx.z;
  const int t = threadIdx.x, lane = t & 63, w = t >> 6;
  const int r16 = lane & 15, g = lane >> 4;
  __shared__ unsigned short lK[2][128 * 64];   // 128 K-rows x 64 d
  __shared__ unsigned short lV[2][64 * 128];   // 64 d-rows x 128 k
  __shared__ unsigned short lP[4][16 * 128];   // per-wave P^T

  const int qtA = j, qtB = 31 - j;         // 64-row q-tiles, qtA <= qtB
  const int ktA = qtA >> 1, ktB = qtB >> 1;  // last 128-wide k-tile per q-tile
  const int qrowA = qtA * 64 + w * 16 + r16;
  const int qrowB = qtB * 64 + w * 16 + r16;
  const float CE = 0.18033688011112042f;   // (1/8) * log2(e)

  bf16x8 qfA[2], qfB[2];
  {
    const unsigned short* qa = qk + (size_t)(bb * 2048 + qrowA) * 2048 + h * 64;
    qfA[0] = *(const bf16x8*)(qa + g * 8);
    qfA[1] = *(const bf16x8*)(qa + 32 + g * 8);
    const unsigned short* qb = qk + (size_t)(bb * 2048 + qrowB) * 2048 + h * 64;
    qfB[0] = *(const bf16x8*)(qb + g * 8);
    qfB[1] = *(const bf16x8*)(qb + 32 + g * 8);
  }

  f32x4 accA[4] = {}, accB[4] = {};
  float mA = -3.0e38f, lA_ = 0.0f, mB = -3.0e38f, lB_ = 0.0f;

  auto stage = [&](int buf, int kt) {
    const int k0 = kt * 128;
#pragma unroll
    for (int p = 0; p < 4; ++p) {
      const int ci = t + p * 256;
      // K: 128 rows x 8 chunks of 8 bf16
      const int r = ci >> 3, cs = ci & 7;
      GLDS(qk + (size_t)(bb * 2048 + k0 + r) * 2048 + 1024 + h * 64 +
               (cs ^ (r & 7)) * 8,
           &lK[buf][ci * 8]);
      // V: 64 rows x 16 chunks of 8 bf16 (XOR on low 3 chunk bits)
      const int r2 = ci >> 4, cs2 = ci & 15;
      GLDS(vt + ((size_t)bb * 1024 + h * 64 + r2) * 2048 + k0 +
               (cs2 ^ (r2 & 7)) * 8,
           &lV[buf][ci * 8]);
    }
  };

  const int pswz = (r16 & 7) << 3;  // lP XOR swizzle (8-elem granules)

  auto flash_step = [&](const bf16x8* qf, f32x4* accO, float& mrun,
                        float& lrun, int qrow, bool diag, int k0, int cur) {
    f32x4 s[8] = {};
    __builtin_amdgcn_s_setprio(1);
#pragma unroll
    for (int ks = 0; ks < 2; ++ks)
#pragma unroll
      for (int mt = 0; mt < 8; ++mt) {
        const int r = mt * 16 + r16, db = ks * 4 + g;
        const bf16x8 kf =
            *(const bf16x8*)&lK[cur][((r << 3) + (db ^ (r & 7))) << 3];
        s[mt] = __builtin_amdgcn_mfma_f32_16x16x32_bf16(kf, qf[ks], s[mt],
                                                        0, 0, 0);
      }
    __builtin_amdgcn_s_setprio(0);
    if (diag) {
#pragma unroll
      for (int mt = 0; mt < 8; ++mt)
#pragma unroll
        for (int r = 0; r < 4; ++r)
          if (k0 + mt * 16 + g * 4 + r > qrow) s[mt][r] = -3.0e38f;
    }
    float tmax = -3.0e38f;
#pragma unroll
    for (int mt = 0; mt < 8; ++mt)
#pragma unroll
      for (int r = 0; r < 4; ++r) tmax = fmaxf(tmax, s[mt][r]);
    tmax = fmaxf(tmax, __shfl_xor(tmax, 16));
    tmax = fmaxf(tmax, __shfl_xor(tmax, 32));
    // T13 defer-max: only rescale when the running max grew materially
    if (!__all(tmax <= mrun + 44.0f)) {
      const float mnew = fmaxf(mrun, tmax);
      const float fac = __builtin_amdgcn_exp2f((mrun - mnew) * CE);
      lrun *= fac;
      float fr[4];
#pragma unroll
      for (int r = 0; r < 4; ++r) fr[r] = __shfl(fac, g * 4 + r);
#pragma unroll
      for (int nb = 0; nb < 4; ++nb)
#pragma unroll
        for (int r = 0; r < 4; ++r) accO[nb][r] *= fr[r];
      mrun = mnew;
    }
    float tsum = 0.0f;
#pragma unroll
    for (int mt = 0; mt < 8; ++mt) {
      float pv[4];
#pragma unroll
      for (int r = 0; r < 4; ++r) {
        pv[r] = __builtin_amdgcn_exp2f((s[mt][r] - mrun) * CE);
        tsum += pv[r];
      }
      u32x2 pk;
      pk.x = cvt_pk_bf16(pv[0], pv[1]);
      pk.y = cvt_pk_bf16(pv[2], pv[3]);
      *(u32x2*)&lP[w][r16 * 128 + ((mt * 16 + g * 4) ^ pswz)] = pk;
    }
    tsum += __shfl_xor(tsum, 16);
    tsum += __shfl_xor(tsum, 32);
    lrun += tsum;
    __builtin_amdgcn_s_setprio(1);
#pragma unroll
    for (int ks = 0; ks < 4; ++ks) {
      const bf16x8 pa =
          *(const bf16x8*)&lP[w][r16 * 128 + ((ks * 32 + g * 8) ^ pswz)];
#pragma unroll
      for (int nb = 0; nb < 4; ++nb) {
        const int d = nb * 16 + r16, kb = ks * 4 + g;
        const bf16x8 vf =
            *(const bf16x8*)&lV[cur][((d << 4) + (kb ^ (d & 7))) << 3];
        accO[nb] = __builtin_amdgcn_mfma_f32_16x16x32_bf16(pa, vf, accO[nb],
                                                           0, 0, 0);
      }
    }
    __builtin_amdgcn_s_setprio(0);
  };

  stage(0, 0);
  __syncthreads();
  int cur = 0;
  for (int kt = 0; kt <= ktB; ++kt) {
    if (kt < ktB) stage(cur ^ 1, kt + 1);
    flash_step(qfB, accB, mB, lB_, qrowB, kt == ktB, kt * 128, cur);
    if (kt <= ktA)
      flash_step(qfA, accA, mA, lA_, qrowA, kt == ktA, kt * 128, cur);
    __syncthreads();  // drains vmcnt: staged kt+1 complete + buf[cur] free
    cur ^= 1;
  }

  auto epilogue = [&](const f32x4* accO, float lrun, int q0) {
    const float li = 1.0f / lrun;
    float lr_[4];
#pragma unroll
    for (int r = 0; r < 4; ++r) lr_[r] = __shfl(li, g * 4 + r);
#pragma unroll
    for (int nb = 0; nb < 4; ++nb)
#pragma unroll
      for (int r = 0; r < 4; ++r) {
        const int row = bb * 2048 + q0 + w * 16 + g * 4 + r;
        const int col = h * 64 + nb * 16 + r16;
        obuf[(size_t)row * 1024 + col] = f2b(accO[nb][r] * lr_[r]);
      }
  };
  epilogue(accA, lA_, qtA * 64);
  epilogue(accB, lB_, qtB * 64);
}

// ---------------------------------------------------------------------------
extern "C" void kernel_launch(void* const* d_in, const int* in_sizes, int n_in,
                              void* d_out, int out_size, void* d_ws,
                              size_t ws_size, hipStream_t stream) {
  const float* hs   = (const float*)d_in[0];
  const float* Wq   = (const float*)d_in[1];
  const float* Wk   = (const float*)d_in[2];
  const float* Wv   = (const float*)d_in[3];
  const float* Wo   = (const float*)d_in[4];
  const float* W1   = (const float*)d_in[5];
  const float* b1   = (const float*)d_in[6];
  const float* W2   = (const float*)d_in[7];
  const float* b2   = (const float*)d_in[8];
  const float* ln1s = (const float*)d_in[9];
  const float* ln1b = (const float*)d_in[10];
  const float* ln2s = (const float*)d_in[11];
  const float* ln2b = (const float*)d_in[12];
  float* out = (float*)d_out;

  char* ws = (char*)d_ws;
  unsigned short* wqkvT = (unsigned short*)(ws + 0);          //  6 MB [3072][1024]
  unsigned short* woT   = (unsigned short*)(ws + 6291456);    //  2 MB [1024][1024]
  unsigned short* w1T   = (unsigned short*)(ws + 8388608);    //  8 MB [4096][1024]
  unsigned short* w2T   = (unsigned short*)(ws + 16777216);   //  8 MB [1024][4096]
  float*          hid   = (float*)(ws + 25165824);            // 16 MB [4096][1024]
  unsigned short* xb    = (unsigned short*)(ws + 41943040);   //  8 MB [4096][1024]
  char*           big   = ws + 50331648;                      // 32 MB region
  unsigned short* qkb   = (unsigned short*)(big);             // 16 MB [4096][2048]
  unsigned short* vtb   = (unsigned short*)(big + 16777216);  //  8 MB [2][1024][2048]
  unsigned short* ob    = (unsigned short*)(big + 25165824);  //  8 MB [4096][1024]
  unsigned short* h1    = (unsigned short*)(big);             // 32 MB (reuse) [4096][4096]

  // fused: LN1 + all 6 weight transposes
  prep_kernel<<<16384, 256, 0, stream>>>(hs, ln1s, ln1b, xb,
                                         Wq, Wk, Wv, Wo, W1, W2,
                                         wqkvT, woT, w1T, w2T);
  // QKV projection (256^2 counted-vmcnt pipeline; V written transposed)
  gemm256<0><<<dim3(16, 12), 512, 0, stream>>>(xb, wqkvT, 1024, 3072,
                                               qkb, nullptr, vtb);
  // attention (paired q-tiles, KVBLK=128 -> 17 uniform steps/block)
  attn_kernel<<<dim3(16, 16, 2), 256, 0, stream>>>(qkb, vtb, ob);
  // output projection + residual (BM=64, 2-deep counted-vmcnt)
  gemm_bt<1, 64><<<dim3(64, 8), 256, 0, stream>>>(ob, woT, 1024, 1024,
                                                  hid, nullptr, hs);
  // LN2
  ln_kernel<<<4096, 256, 0, stream>>>(hid, ln2s, ln2b, xb);
  // FFN up + GELU (tanh approx), 256^2 counted-vmcnt pipeline
  gemm256<2><<<dim3(16, 16), 512, 0, stream>>>(xb, w1T, 1024, 4096,
                                               h1, b1, nullptr);
  // FFN down + bias + residual -> out (BM=64, 2-deep counted-vmcnt)
  gemm_bt<3, 64><<<dim3(64, 8), 256, 0, stream>>>(h1, w2T, 4096, 1024,
                                                  out, b2, hid);
}

// Round 10
// 229.866 us; speedup vs baseline: 1.0862x; 1.0862x over previous
//
#include <hip/hip_runtime.h>
#include <math.h>

using bf16x8 = __attribute__((ext_vector_type(8))) short;
using f32x4  = __attribute__((ext_vector_type(4))) float;

struct __align__(8) us4 { unsigned short x, y, z, w; };
struct __align__(8) u32x2 { unsigned int x, y; };

__device__ __forceinline__ unsigned short f2b(float f) {
  union { float f; unsigned u; } v; v.f = f;
  unsigned r = v.u + 0x7FFFu + ((v.u >> 16) & 1u);
  return (unsigned short)(r >> 16);
}
__device__ __forceinline__ unsigned int cvt_pk_bf16(float lo, float hi) {
  unsigned int d;
  asm("v_cvt_pk_bf16_f32 %0, %1, %2" : "=v"(d) : "v"(lo), "v"(hi));
  return d;
}

#define GLDS(g, l) __builtin_amdgcn_global_load_lds(                        \
    (const __attribute__((address_space(1))) void*)(g),                    \
    (__attribute__((address_space(3))) void*)(l), 16, 0, 0)

// ---------------------------------------------------------------------------
// Fused prep: LN1 (blocks 0..4095) + all 6 weight transposes (fp32->bf16,
// [K][N] -> [N][K]) in one dispatch (measured ~-15us vs separate dispatches).
// ---------------------------------------------------------------------------
__global__ void __launch_bounds__(256) prep_kernel(
    const float* __restrict__ hs, const float* __restrict__ ln1s,
    const float* __restrict__ ln1b, unsigned short* __restrict__ xb,
    const float* __restrict__ Wq, const float* __restrict__ Wk,
    const float* __restrict__ Wv, const float* __restrict__ Wo,
    const float* __restrict__ W1, const float* __restrict__ W2,
    unsigned short* __restrict__ wqkvT, unsigned short* __restrict__ woT,
    unsigned short* __restrict__ w1T, unsigned short* __restrict__ w2T) {
  const int id = blockIdx.x;
  const int t = threadIdx.x;
  __shared__ float tile[32][33];
  __shared__ float red[8];

  if (id < 4096) {  // ---- LN1 row ----
    const int row = id;
    const float4 v = ((const float4*)(hs + (size_t)row * 1024))[t];
    float s  = v.x + v.y + v.z + v.w;
    float s2 = v.x * v.x + v.y * v.y + v.z * v.z + v.w * v.w;
#pragma unroll
    for (int off = 32; off; off >>= 1) {
      s  += __shfl_xor(s,  off);
      s2 += __shfl_xor(s2, off);
    }
    const int w = t >> 6, lane = t & 63;
    if (!lane) { red[w] = s; red[4 + w] = s2; }
    __syncthreads();
    s  = red[0] + red[1] + red[2] + red[3];
    s2 = red[4] + red[5] + red[6] + red[7];
    const float mean = s * (1.0f / 1024.0f);
    const float var  = s2 * (1.0f / 1024.0f) - mean * mean;
    const float rstd = rsqrtf(var + 1e-5f);
    const float4 sc = ((const float4*)ln1s)[t];
    const float4 sh = ((const float4*)ln1b)[t];
    us4 o;
    o.x = f2b((v.x - mean) * rstd * sc.x + sh.x);
    o.y = f2b((v.y - mean) * rstd * sc.y + sh.y);
    o.z = f2b((v.z - mean) * rstd * sc.z + sh.z);
    o.w = f2b((v.w - mean) * rstd * sc.w + sh.w);
    ((us4*)(xb + (size_t)row * 1024))[t] = o;
    return;
  }

  // ---- weight transpose tile ----
  const float* src; unsigned short* dst; int K, N, n0, k0;
  if (id < 8192) {            // Wq/Wk/Wv/Wo: 1024x1024, 32x32 grids
    const int which = (id - 4096) >> 10, local = (id - 4096) & 1023;
    src = (which == 0) ? Wq : (which == 1) ? Wk : (which == 2) ? Wv : Wo;
    dst = (which == 3) ? woT : wqkvT + (size_t)which * 1048576;
    K = 1024; N = 1024;
    n0 = (local & 31) * 32; k0 = (local >> 5) * 32;
  } else if (id < 12288) {    // W1: K=1024, N=4096, grid (128,32)
    const int local = id - 8192;
    src = W1; dst = w1T; K = 1024; N = 4096;
    n0 = (local & 127) * 32; k0 = (local >> 7) * 32;
  } else {                    // W2: K=4096, N=1024, grid (32,128)
    const int local = id - 12288;
    src = W2; dst = w2T; K = 4096; N = 1024;
    n0 = (local & 31) * 32; k0 = (local >> 5) * 32;
  }
  const int tx = t & 31, ty = t >> 5;  // 32 x 8
#pragma unroll
  for (int i = 0; i < 32; i += 8)
    tile[ty + i][tx] = src[(size_t)(k0 + ty + i) * N + n0 + tx];
  __syncthreads();
#pragma unroll
  for (int i = 0; i < 32; i += 8)
    dst[(size_t)(n0 + ty + i) * K + k0 + tx] = f2b(tile[tx][ty + i]);
}

// ---------------------------------------------------------------------------
// LayerNorm over last dim (1024), fp32 in -> bf16 out (LN2)
// ---------------------------------------------------------------------------
__global__ void __launch_bounds__(256) ln_kernel(
    const float* __restrict__ in, const float* __restrict__ scale,
    const float* __restrict__ shift, unsigned short* __restrict__ out) {
  const int row = blockIdx.x, t = threadIdx.x;
  const float4 v = ((const float4*)(in + (size_t)row * 1024))[t];
  float s  = v.x + v.y + v.z + v.w;
  float s2 = v.x * v.x + v.y * v.y + v.z * v.z + v.w * v.w;
#pragma unroll
  for (int off = 32; off; off >>= 1) {
    s  += __shfl_xor(s,  off);
    s2 += __shfl_xor(s2, off);
  }
  __shared__ float red[8];
  const int w = t >> 6, lane = t & 63;
  if (!lane) { red[w] = s; red[4 + w] = s2; }
  __syncthreads();
  s  = red[0] + red[1] + red[2] + red[3];
  s2 = red[4] + red[5] + red[6] + red[7];
  const float mean = s * (1.0f / 1024.0f);
  const float var  = s2 * (1.0f / 1024.0f) - mean * mean;
  const float rstd = rsqrtf(var + 1e-5f);
  const float4 sc = ((const float4*)scale)[t];
  const float4 sh = ((const float4*)shift)[t];
  us4 o;
  o.x = f2b((v.x - mean) * rstd * sc.x + sh.x);
  o.y = f2b((v.y - mean) * rstd * sc.y + sh.y);
  o.z = f2b((v.z - mean) * rstd * sc.z + sh.z);
  o.w = f2b((v.w - mean) * rstd * sc.w + sh.w);
  ((us4*)(out + (size_t)row * 1024))[t] = o;
}

// ---------------------------------------------------------------------------
// 256x256 GEMM, 8 waves (2M x 4N), BK=64, counted-vmcnt pipeline (round-6
// version — best measured). MODE 0: qkv split -> qk + vt (V^T).
// MODE 2: out_bf16 = gelu_tanh(acc + bias)
// ---------------------------------------------------------------------------
template <int MODE>
__global__ void __launch_bounds__(512, 2) gemm256(
    const unsigned short* __restrict__ A, const unsigned short* __restrict__ B,
    int K, int N, unsigned short* __restrict__ outb,
    const float* __restrict__ bias, unsigned short* __restrict__ vt) {
  __shared__ unsigned short lA[2][256 * 64];
  __shared__ unsigned short lB[2][256 * 64];
  const int t = threadIdx.x, lane = t & 63;
  const int w = t >> 6, wm = w >> 2, wn = w & 3;
  const int r16 = lane & 15, g = lane >> 4;
  const int m0 = blockIdx.x * 256, n0 = blockIdx.y * 256;

  const unsigned short* aSrc[4];
  const unsigned short* bSrc[4];
#pragma unroll
  for (int p = 0; p < 4; ++p) {
    const int ci = t + p * 512, r = ci >> 3, cs = ci & 7;
    aSrc[p] = A + (size_t)(m0 + r) * K + (cs ^ (r & 7)) * 8;
    bSrc[p] = B + (size_t)(n0 + r) * K + (cs ^ (r & 7)) * 8;
  }
  int aOff[8][2], bOff[4][2];
#pragma unroll
  for (int i = 0; i < 8; ++i)
#pragma unroll
    for (int ks = 0; ks < 2; ++ks) {
      const int m = wm * 128 + i * 16 + r16, kb = ks * 4 + g;
      aOff[i][ks] = ((m << 3) + (kb ^ (m & 7))) << 3;
    }
#pragma unroll
  for (int j = 0; j < 4; ++j)
#pragma unroll
    for (int ks = 0; ks < 2; ++ks) {
      const int n = wn * 64 + j * 16 + r16, kb = ks * 4 + g;
      bOff[j][ks] = ((n << 3) + (kb ^ (n & 7))) << 3;
    }

  auto stage = [&](int buf, int kt) {
    const int off = kt * 64;
#pragma unroll
    for (int p = 0; p < 4; ++p) {
      GLDS(aSrc[p] + off, &lA[buf][(t + p * 512) * 8]);
      GLDS(bSrc[p] + off, &lB[buf][(t + p * 512) * 8]);
    }
  };

  f32x4 acc[8][4] = {};
  const int nkt = K >> 6;
  stage(0, 0);
  for (int kt = 0; kt < nkt; ++kt) {
    const int cur = kt & 1;
    if (kt + 1 < nkt) {
      stage(cur ^ 1, kt + 1);  // 8 loads into buf[cur^1], left in flight
      asm volatile("s_waitcnt vmcnt(8)" ::: "memory");  // buf[cur] landed
    } else {
      asm volatile("s_waitcnt vmcnt(0)" ::: "memory");
    }
    __builtin_amdgcn_s_barrier();          // all waves: buf[cur] staged
    __builtin_amdgcn_sched_barrier(0);     // no LDS reads hoisted above
    const unsigned short* bA = lA[cur];
    const unsigned short* bB = lB[cur];
#pragma unroll
    for (int ks = 0; ks < 2; ++ks) {
      bf16x8 af[8], bfr[4];
#pragma unroll
      for (int i = 0; i < 8; ++i) af[i] = *(const bf16x8*)&bA[aOff[i][ks]];
#pragma unroll
      for (int j = 0; j < 4; ++j) bfr[j] = *(const bf16x8*)&bB[bOff[j][ks]];
      __builtin_amdgcn_s_setprio(1);
#pragma unroll
      for (int i = 0; i < 8; ++i)
#pragma unroll
        for (int j = 0; j < 4; ++j)
          acc[i][j] = __builtin_amdgcn_mfma_f32_16x16x32_bf16(
              af[i], bfr[j], acc[i][j], 0, 0, 0);
      __builtin_amdgcn_s_setprio(0);
    }
    __builtin_amdgcn_sched_barrier(0);     // no next-iter GLDS hoisted above
    __builtin_amdgcn_s_barrier();          // all waves done reading buf[cur]
  }

  float bj[4];
  if constexpr (MODE == 2) {
#pragma unroll
    for (int j = 0; j < 4; ++j) bj[j] = bias[n0 + wn * 64 + j * 16 + r16];
  }
#pragma unroll
  for (int i = 0; i < 8; ++i) {
    const int row0 = m0 + wm * 128 + i * 16 + g * 4;
#pragma unroll
    for (int j = 0; j < 4; ++j) {
      const int colb = n0 + wn * 64 + j * 16;
      const int col = colb + r16;
      if constexpr (MODE == 0) {
        if (colb < 2048) {
#pragma unroll
          for (int r = 0; r < 4; ++r)
            outb[(size_t)(row0 + r) * 2048 + col] = f2b(acc[i][j][r]);
        } else {
          const int b = row0 >> 11, s0 = row0 & 2047;
          us4 pk;
          pk.x = f2b(acc[i][j][0]); pk.y = f2b(acc[i][j][1]);
          pk.z = f2b(acc[i][j][2]); pk.w = f2b(acc[i][j][3]);
          *(us4*)&vt[((size_t)b * 1024 + (col - 2048)) * 2048 + s0] = pk;
        }
      } else {
#pragma unroll
        for (int r = 0; r < 4; ++r) {
          const float x = acc[i][j][r] + bj[j];
          const float u = x * (0.7978845608028654f + 0.03567740814f * x * x);
          const float e = __builtin_amdgcn_exp2f(u * 2.885390081777927f);
          const float th = 1.0f - 2.0f * __builtin_amdgcn_rcpf(e + 1.0f);
          outb[(size_t)(row0 + r) * N + col] = f2b(0.5f * x * (1.0f + th));
        }
      }
    }
  }
}

// ---------------------------------------------------------------------------
// GEMM: C[M,N] = A[M,K](bf16) * B^T, B stored [N,K]. BMx128 tile, 4 waves.
// 2-deep counted-vmcnt pipeline (round-6 version). N=1024 GEMMs (Wo, FFN-dn).
// MODE 1: out_f32 = acc + resid ; MODE 3: out_f32 = acc + bias + resid
// ---------------------------------------------------------------------------
template <int MODE, int BM>
__global__ void __launch_bounds__(256) gemm_bt(
    const unsigned short* __restrict__ A, const unsigned short* __restrict__ B,
    int K, int N,
    float* __restrict__ outf, const float* __restrict__ bias,
    const float* __restrict__ resid) {
  constexpr int WN = (BM == 128) ? 2 : 4;   // waves along N
  constexpr int NJ = 128 / (16 * WN);       // N-fragments per wave
  constexpr int ACH = BM / 32;              // A staging passes
  __shared__ unsigned short lA[2][BM * 64];
  __shared__ unsigned short lB[2][128 * 64];
  const int t = threadIdx.x, lane = t & 63;
  const int w = t >> 6, wm = w / WN, wn = w % WN;
  const int r16 = lane & 15, g = lane >> 4;
  const int m0 = blockIdx.x * BM, n0 = blockIdx.y * 128;

  const unsigned short* aSrc[ACH];
  const unsigned short* bSrc[4];
#pragma unroll
  for (int p = 0; p < ACH; ++p) {
    const int ci = t + p * 256, m = ci >> 3, cs = ci & 7;
    aSrc[p] = A + (size_t)(m0 + m) * K + (cs ^ (m & 7)) * 8;
  }
#pragma unroll
  for (int p = 0; p < 4; ++p) {
    const int ci = t + p * 256, m = ci >> 3, cs = ci & 7;
    bSrc[p] = B + (size_t)(n0 + m) * K + (cs ^ (m & 7)) * 8;
  }

  int aOff[4][2], bOff[NJ][2];
#pragma unroll
  for (int i = 0; i < 4; ++i)
#pragma unroll
    for (int ks = 0; ks < 2; ++ks) {
      const int m = wm * 64 + i * 16 + r16, kb = ks * 4 + g;
      aOff[i][ks] = ((m << 3) + (kb ^ (m & 7))) << 3;
    }
#pragma unroll
  for (int j = 0; j < NJ; ++j)
#pragma unroll
    for (int ks = 0; ks < 2; ++ks) {
      const int n = wn * (16 * NJ) + j * 16 + r16, kb = ks * 4 + g;
      bOff[j][ks] = ((n << 3) + (kb ^ (n & 7))) << 3;
    }

  auto stage = [&](int buf, int kt) {
    const int off = kt * 64;
#pragma unroll
    for (int p = 0; p < ACH; ++p)
      GLDS(aSrc[p] + off, &lA[buf][(t + p * 256) * 8]);
#pragma unroll
    for (int p = 0; p < 4; ++p)
      GLDS(bSrc[p] + off, &lB[buf][(t + p * 256) * 8]);
  };

  f32x4 acc[4][NJ] = {};
  const int nkt = K >> 6;
  stage(0, 0);
  for (int kt = 0; kt < nkt; ++kt) {
    const int cur = kt & 1;
    if (kt + 1 < nkt) {
      stage(cur ^ 1, kt + 1);  // 6 loads into buf[cur^1], left in flight
      if constexpr (ACH == 2)
        asm volatile("s_waitcnt vmcnt(6)" ::: "memory");  // buf[cur] landed
      else
        asm volatile("s_waitcnt vmcnt(8)" ::: "memory");
    } else {
      asm volatile("s_waitcnt vmcnt(0)" ::: "memory");
    }
    __builtin_amdgcn_s_barrier();          // all waves: buf[cur] staged
    __builtin_amdgcn_sched_barrier(0);     // no LDS reads hoisted above
    const unsigned short* bA = lA[cur];
    const unsigned short* bB = lB[cur];
#pragma unroll
    for (int ks = 0; ks < 2; ++ks) {
      bf16x8 af[4], bfr[NJ];
#pragma unroll
      for (int i = 0; i < 4; ++i) af[i] = *(const bf16x8*)&bA[aOff[i][ks]];
#pragma unroll
      for (int j = 0; j < NJ; ++j) bfr[j] = *(const bf16x8*)&bB[bOff[j][ks]];
      __builtin_amdgcn_s_setprio(1);
#pragma unroll
      for (int i = 0; i < 4; ++i)
#pragma unroll
        for (int j = 0; j < NJ; ++j)
          acc[i][j] = __builtin_amdgcn_mfma_f32_16x16x32_bf16(
              af[i], bfr[j], acc[i][j], 0, 0, 0);
      __builtin_amdgcn_s_setprio(0);
    }
    __builtin_amdgcn_sched_barrier(0);     // no next-iter GLDS hoisted above
    __builtin_amdgcn_s_barrier();          // all waves done reading buf[cur]
  }

  float bj[NJ];
  if constexpr (MODE == 3) {
#pragma unroll
    for (int j = 0; j < NJ; ++j)
      bj[j] = bias[n0 + wn * (16 * NJ) + j * 16 + r16];
  }
#pragma unroll
  for (int i = 0; i < 4; ++i) {
    const int row0 = m0 + wm * 64 + i * 16 + g * 4;
#pragma unroll
    for (int j = 0; j < NJ; ++j) {
      const int col = n0 + wn * (16 * NJ) + j * 16 + r16;
      if constexpr (MODE == 1) {
#pragma unroll
        for (int r = 0; r < 4; ++r) {
          const size_t idx = (size_t)(row0 + r) * N + col;
          outf[idx] = acc[i][j][r] + resid[idx];
        }
      } else {
#pragma unroll
        for (int r = 0; r < 4; ++r) {
          const size_t idx = (size_t)(row0 + r) * N + col;
          outf[idx] = acc[i][j][r] + bj[j] + resid[idx];
        }
      }
    }
  }
}

// ---------------------------------------------------------------------------
// Flash attention (causal), load-balanced: block j handles q-tiles j and 31-j
// (33 compute-steps/block, one shared K/V staging pass). Grid (16,16,2),
// 4 waves, KVBLK=64 (round-6 version — best measured; KVBLK=128 regressed:
// occupancy 16.8->9.3%, bank conflicts 1.1M->3.3M).
// T5 setprio, T13 defer-max (THR=44 raw), cvt_pk packing, XOR-swizzled lP.
// ---------------------------------------------------------------------------
__global__ void __launch_bounds__(256) attn_kernel(
    const unsigned short* __restrict__ qk, const unsigned short* __restrict__ vt,
    unsigned short* __restrict__ obuf) {
  const int j = blockIdx.x, h = blockIdx.y, bb = blockIdx.z;
  const int t = threadIdx.x, lane = t & 63, w = t >> 6;
  const int r16 = lane & 15, g = lane >> 4;
  __shared__ unsigned short lK[2][64 * 64];
  __shared__ unsigned short lV[2][64 * 64];
  __shared__ unsigned short lP[4][16 * 64];

  const int qtA = j, qtB = 31 - j;   // qtA <= qtB
  const int ktmax = qtB;
  const int qrowA = qtA * 64 + w * 16 + r16;
  const int qrowB = qtB * 64 + w * 16 + r16;
  const float CE = 0.18033688011112042f;  // (1/8) * log2(e)

  bf16x8 qfA[2], qfB[2];
  {
    const unsigned short* qa = qk + (size_t)(bb * 2048 + qrowA) * 2048 + h * 64;
    qfA[0] = *(const bf16x8*)(qa + g * 8);
    qfA[1] = *(const bf16x8*)(qa + 32 + g * 8);
    const unsigned short* qb = qk + (size_t)(bb * 2048 + qrowB) * 2048 + h * 64;
    qfB[0] = *(const bf16x8*)(qb + g * 8);
    qfB[1] = *(const bf16x8*)(qb + 32 + g * 8);
  }

  f32x4 accA[4] = {}, accB[4] = {};
  float mA = -3.0e38f, lA_ = 0.0f, mB = -3.0e38f, lB_ = 0.0f;

  auto stage = [&](int buf, int kt) {
    const int k0 = kt * 64;
#pragma unroll
    for (int p = 0; p < 2; ++p) {
      const int ci = t + p * 256;
      const int r = ci >> 3, cs = ci & 7;
      const int cb = cs ^ (r & 7);
      GLDS(qk + (size_t)(bb * 2048 + k0 + r) * 2048 + 1024 + h * 64 + cb * 8,
           &lK[buf][ci * 8]);
      GLDS(vt + ((size_t)bb * 1024 + h * 64 + r) * 2048 + k0 + cb * 8,
           &lV[buf][ci * 8]);
    }
  };

  const int pswz = (r16 & 7) << 3;  // lP XOR swizzle (8-elem granules)

  auto flash_step = [&](const bf16x8* qf, f32x4* accO, float& mrun,
                        float& lrun, int qrow, bool diag, int k0, int cur) {
    f32x4 s[4] = {};
    __builtin_amdgcn_s_setprio(1);
#pragma unroll
    for (int ks = 0; ks < 2; ++ks)
#pragma unroll
      for (int mt = 0; mt < 4; ++mt) {
        const int r = mt * 16 + r16, db = ks * 4 + g;
        const bf16x8 kf =
            *(const bf16x8*)&lK[cur][((r << 3) + (db ^ (r & 7))) << 3];
        s[mt] = __builtin_amdgcn_mfma_f32_16x16x32_bf16(kf, qf[ks], s[mt],
                                                        0, 0, 0);
      }
    __builtin_amdgcn_s_setprio(0);
    if (diag) {
#pragma unroll
      for (int mt = 0; mt < 4; ++mt)
#pragma unroll
        for (int r = 0; r < 4; ++r)
          if (k0 + mt * 16 + g * 4 + r > qrow) s[mt][r] = -3.0e38f;
    }
    float tmax = -3.0e38f;
#pragma unroll
    for (int mt = 0; mt < 4; ++mt)
#pragma unroll
      for (int r = 0; r < 4; ++r) tmax = fmaxf(tmax, s[mt][r]);
    tmax = fmaxf(tmax, __shfl_xor(tmax, 16));
    tmax = fmaxf(tmax, __shfl_xor(tmax, 32));
    // T13 defer-max: only rescale when the running max grew materially
    if (!__all(tmax <= mrun + 44.0f)) {
      const float mnew = fmaxf(mrun, tmax);
      const float fac = __builtin_amdgcn_exp2f((mrun - mnew) * CE);
      lrun *= fac;
      float fr[4];
#pragma unroll
      for (int r = 0; r < 4; ++r) fr[r] = __shfl(fac, g * 4 + r);
#pragma unroll
      for (int nb = 0; nb < 4; ++nb)
#pragma unroll
        for (int r = 0; r < 4; ++r) accO[nb][r] *= fr[r];
      mrun = mnew;
    }
    float pv[4][4];
    float tsum = 0.0f;
#pragma unroll
    for (int mt = 0; mt < 4; ++mt)
#pragma unroll
      for (int r = 0; r < 4; ++r) {
        pv[mt][r] = __builtin_amdgcn_exp2f((s[mt][r] - mrun) * CE);
        tsum += pv[mt][r];
      }
    tsum += __shfl_xor(tsum, 16);
    tsum += __shfl_xor(tsum, 32);
    lrun += tsum;
    // write P^T (per-wave region, XOR-swizzled, cvt_pk packed)
#pragma unroll
    for (int mt = 0; mt < 4; ++mt) {
      u32x2 pk;
      pk.x = cvt_pk_bf16(pv[mt][0], pv[mt][1]);
      pk.y = cvt_pk_bf16(pv[mt][2], pv[mt][3]);
      *(u32x2*)&lP[w][r16 * 64 + ((mt * 16 + g * 4) ^ pswz)] = pk;
    }
    __builtin_amdgcn_s_setprio(1);
#pragma unroll
    for (int ks = 0; ks < 2; ++ks) {
      const bf16x8 pa =
          *(const bf16x8*)&lP[w][r16 * 64 + ((ks * 32 + g * 8) ^ pswz)];
#pragma unroll
      for (int nb = 0; nb < 4; ++nb) {
        const int d = nb * 16 + r16, kb = ks * 4 + g;
        const bf16x8 vf =
            *(const bf16x8*)&lV[cur][((d << 3) + (kb ^ (d & 7))) << 3];
        accO[nb] = __builtin_amdgcn_mfma_f32_16x16x32_bf16(pa, vf, accO[nb],
                                                           0, 0, 0);
      }
    }
    __builtin_amdgcn_s_setprio(0);
  };

  stage(0, 0);
  __syncthreads();
  int cur = 0;
  for (int kt = 0; kt <= ktmax; ++kt) {
    if (kt < ktmax) stage(cur ^ 1, kt + 1);
    flash_step(qfB, accB, mB, lB_, qrowB, kt == qtB, kt * 64, cur);
    if (kt <= qtA)
      flash_step(qfA, accA, mA, lA_, qrowA, kt == qtA, kt * 64, cur);
    __syncthreads();  // drains vmcnt: staged kt+1 complete + lK/lV[cur] free
    cur ^= 1;
  }

  auto epilogue = [&](const f32x4* accO, float lrun, int q0) {
    const float li = 1.0f / lrun;
    float lr_[4];
#pragma unroll
    for (int r = 0; r < 4; ++r) lr_[r] = __shfl(li, g * 4 + r);
#pragma unroll
    for (int nb = 0; nb < 4; ++nb)
#pragma unroll
      for (int r = 0; r < 4; ++r) {
        const int row = bb * 2048 + q0 + w * 16 + g * 4 + r;
        const int col = h * 64 + nb * 16 + r16;
        obuf[(size_t)row * 1024 + col] = f2b(accO[nb][r] * lr_[r]);
      }
  };
  epilogue(accA, lA_, qtA * 64);
  epilogue(accB, lB_, qtB * 64);
}

// ---------------------------------------------------------------------------
extern "C" void kernel_launch(void* const* d_in, const int* in_sizes, int n_in,
                              void* d_out, int out_size, void* d_ws,
                              size_t ws_size, hipStream_t stream) {
  const float* hs   = (const float*)d_in[0];
  const float* Wq   = (const float*)d_in[1];
  const float* Wk   = (const float*)d_in[2];
  const float* Wv   = (const float*)d_in[3];
  const float* Wo   = (const float*)d_in[4];
  const float* W1   = (const float*)d_in[5];
  const float* b1   = (const float*)d_in[6];
  const float* W2   = (const float*)d_in[7];
  const float* b2   = (const float*)d_in[8];
  const float* ln1s = (const float*)d_in[9];
  const float* ln1b = (const float*)d_in[10];
  const float* ln2s = (const float*)d_in[11];
  const float* ln2b = (const float*)d_in[12];
  float* out = (float*)d_out;

  char* ws = (char*)d_ws;
  unsigned short* wqkvT = (unsigned short*)(ws + 0);          //  6 MB [3072][1024]
  unsigned short* woT   = (unsigned short*)(ws + 6291456);    //  2 MB [1024][1024]
  unsigned short* w1T   = (unsigned short*)(ws + 8388608);    //  8 MB [4096][1024]
  unsigned short* w2T   = (unsigned short*)(ws + 16777216);   //  8 MB [1024][4096]
  float*          hid   = (float*)(ws + 25165824);            // 16 MB [4096][1024]
  unsigned short* xb    = (unsigned short*)(ws + 41943040);   //  8 MB [4096][1024]
  char*           big   = ws + 50331648;                      // 32 MB region
  unsigned short* qkb   = (unsigned short*)(big);             // 16 MB [4096][2048]
  unsigned short* vtb   = (unsigned short*)(big + 16777216);  //  8 MB [2][1024][2048]
  unsigned short* ob    = (unsigned short*)(big + 25165824);  //  8 MB [4096][1024]
  unsigned short* h1    = (unsigned short*)(big);             // 32 MB (reuse) [4096][4096]

  // fused: LN1 + all 6 weight transposes
  prep_kernel<<<16384, 256, 0, stream>>>(hs, ln1s, ln1b, xb,
                                         Wq, Wk, Wv, Wo, W1, W2,
                                         wqkvT, woT, w1T, w2T);
  // QKV projection (256^2 counted-vmcnt pipeline; V written transposed)
  gemm256<0><<<dim3(16, 12), 512, 0, stream>>>(xb, wqkvT, 1024, 3072,
                                               qkb, nullptr, vtb);
  // attention (paired q-tiles, KVBLK=64 + micro-opts)
  attn_kernel<<<dim3(16, 16, 2), 256, 0, stream>>>(qkb, vtb, ob);
  // output projection + residual (BM=64, 2-deep counted-vmcnt)
  gemm_bt<1, 64><<<dim3(64, 8), 256, 0, stream>>>(ob, woT, 1024, 1024,
                                                  hid, nullptr, hs);
  // LN2
  ln_kernel<<<4096, 256, 0, stream>>>(hid, ln2s, ln2b, xb);
  // FFN up + GELU (tanh approx), 256^2 counted-vmcnt pipeline
  gemm256<2><<<dim3(16, 16), 512, 0, stream>>>(xb, w1T, 1024, 4096,
                                               h1, b1, nullptr);
  // FFN down + bias + residual -> out (BM=64, 2-deep counted-vmcnt)
  gemm_bt<3, 64><<<dim3(64, 8), 256, 0, stream>>>(h1, w2T, 4096, 1024,
                                                  out, b2, hid);
}

// Round 11
// 229.598 us; speedup vs baseline: 1.0874x; 1.0012x over previous
//
#include <hip/hip_runtime.h>
#include <math.h>

using bf16x8 = __attribute__((ext_vector_type(8))) short;
using f32x4  = __attribute__((ext_vector_type(4))) float;

struct __align__(8) us4 { unsigned short x, y, z, w; };
struct __align__(8) u32x2 { unsigned int x, y; };

__device__ __forceinline__ unsigned short f2b(float f) {
  union { float f; unsigned u; } v; v.f = f;
  unsigned r = v.u + 0x7FFFu + ((v.u >> 16) & 1u);
  return (unsigned short)(r >> 16);
}
__device__ __forceinline__ unsigned int cvt_pk_bf16(float lo, float hi) {
  unsigned int d;
  asm("v_cvt_pk_bf16_f32 %0, %1, %2" : "=v"(d) : "v"(lo), "v"(hi));
  return d;
}

#define GLDS(g, l) __builtin_amdgcn_global_load_lds(                        \
    (const __attribute__((address_space(1))) void*)(g),                    \
    (__attribute__((address_space(3))) void*)(l), 16, 0, 0)

// ---------------------------------------------------------------------------
// Fused prep: LN1 (blocks 0..4095) + all 6 weight transposes (fp32->bf16,
// [K][N] -> [N][K]) in one dispatch (measured ~-15us vs separate dispatches).
// ---------------------------------------------------------------------------
__global__ void __launch_bounds__(256) prep_kernel(
    const float* __restrict__ hs, const float* __restrict__ ln1s,
    const float* __restrict__ ln1b, unsigned short* __restrict__ xb,
    const float* __restrict__ Wq, const float* __restrict__ Wk,
    const float* __restrict__ Wv, const float* __restrict__ Wo,
    const float* __restrict__ W1, const float* __restrict__ W2,
    unsigned short* __restrict__ wqkvT, unsigned short* __restrict__ woT,
    unsigned short* __restrict__ w1T, unsigned short* __restrict__ w2T) {
  const int id = blockIdx.x;
  const int t = threadIdx.x;
  __shared__ float tile[32][33];
  __shared__ float red[8];

  if (id < 4096) {  // ---- LN1 row ----
    const int row = id;
    const float4 v = ((const float4*)(hs + (size_t)row * 1024))[t];
    float s  = v.x + v.y + v.z + v.w;
    float s2 = v.x * v.x + v.y * v.y + v.z * v.z + v.w * v.w;
#pragma unroll
    for (int off = 32; off; off >>= 1) {
      s  += __shfl_xor(s,  off);
      s2 += __shfl_xor(s2, off);
    }
    const int w = t >> 6, lane = t & 63;
    if (!lane) { red[w] = s; red[4 + w] = s2; }
    __syncthreads();
    s  = red[0] + red[1] + red[2] + red[3];
    s2 = red[4] + red[5] + red[6] + red[7];
    const float mean = s * (1.0f / 1024.0f);
    const float var  = s2 * (1.0f / 1024.0f) - mean * mean;
    const float rstd = rsqrtf(var + 1e-5f);
    const float4 sc = ((const float4*)ln1s)[t];
    const float4 sh = ((const float4*)ln1b)[t];
    us4 o;
    o.x = f2b((v.x - mean) * rstd * sc.x + sh.x);
    o.y = f2b((v.y - mean) * rstd * sc.y + sh.y);
    o.z = f2b((v.z - mean) * rstd * sc.z + sh.z);
    o.w = f2b((v.w - mean) * rstd * sc.w + sh.w);
    ((us4*)(xb + (size_t)row * 1024))[t] = o;
    return;
  }

  // ---- weight transpose tile ----
  const float* src; unsigned short* dst; int K, N, n0, k0;
  if (id < 8192) {            // Wq/Wk/Wv/Wo: 1024x1024, 32x32 grids
    const int which = (id - 4096) >> 10, local = (id - 4096) & 1023;
    src = (which == 0) ? Wq : (which == 1) ? Wk : (which == 2) ? Wv : Wo;
    dst = (which == 3) ? woT : wqkvT + (size_t)which * 1048576;
    K = 1024; N = 1024;
    n0 = (local & 31) * 32; k0 = (local >> 5) * 32;
  } else if (id < 12288) {    // W1: K=1024, N=4096, grid (128,32)
    const int local = id - 8192;
    src = W1; dst = w1T; K = 1024; N = 4096;
    n0 = (local & 127) * 32; k0 = (local >> 7) * 32;
  } else {                    // W2: K=4096, N=1024, grid (32,128)
    const int local = id - 12288;
    src = W2; dst = w2T; K = 4096; N = 1024;
    n0 = (local & 31) * 32; k0 = (local >> 5) * 32;
  }
  const int tx = t & 31, ty = t >> 5;  // 32 x 8
#pragma unroll
  for (int i = 0; i < 32; i += 8)
    tile[ty + i][tx] = src[(size_t)(k0 + ty + i) * N + n0 + tx];
  __syncthreads();
#pragma unroll
  for (int i = 0; i < 32; i += 8)
    dst[(size_t)(n0 + ty + i) * K + k0 + tx] = f2b(tile[tx][ty + i]);
}

// ---------------------------------------------------------------------------
// LayerNorm over last dim (1024), fp32 in -> bf16 out (LN2)
// ---------------------------------------------------------------------------
__global__ void __launch_bounds__(256) ln_kernel(
    const float* __restrict__ in, const float* __restrict__ scale,
    const float* __restrict__ shift, unsigned short* __restrict__ out) {
  const int row = blockIdx.x, t = threadIdx.x;
  const float4 v = ((const float4*)(in + (size_t)row * 1024))[t];
  float s  = v.x + v.y + v.z + v.w;
  float s2 = v.x * v.x + v.y * v.y + v.z * v.z + v.w * v.w;
#pragma unroll
  for (int off = 32; off; off >>= 1) {
    s  += __shfl_xor(s,  off);
    s2 += __shfl_xor(s2, off);
  }
  __shared__ float red[8];
  const int w = t >> 6, lane = t & 63;
  if (!lane) { red[w] = s; red[4 + w] = s2; }
  __syncthreads();
  s  = red[0] + red[1] + red[2] + red[3];
  s2 = red[4] + red[5] + red[6] + red[7];
  const float mean = s * (1.0f / 1024.0f);
  const float var  = s2 * (1.0f / 1024.0f) - mean * mean;
  const float rstd = rsqrtf(var + 1e-5f);
  const float4 sc = ((const float4*)scale)[t];
  const float4 sh = ((const float4*)shift)[t];
  us4 o;
  o.x = f2b((v.x - mean) * rstd * sc.x + sh.x);
  o.y = f2b((v.y - mean) * rstd * sc.y + sh.y);
  o.z = f2b((v.z - mean) * rstd * sc.z + sh.z);
  o.w = f2b((v.w - mean) * rstd * sc.w + sh.w);
  ((us4*)(out + (size_t)row * 1024))[t] = o;
}

// ---------------------------------------------------------------------------
// Single-buffered 128x128 GEMM (m97 structure): 32KB LDS -> 3-4 blocks/CU;
// cross-block TLP hides the barrier drain (one block's stage overlaps other
// blocks' MFMA). Hoisted pointers/offsets; 4 waves (2x2), per-wave 64x64.
// Loop: [barrier: readers done] -> stage (8 GLDS) -> barrier (drains vmcnt)
// -> compute. Used for the big-N GEMMs (QKV, FFN-up).
// MODE 0: qkv split -> qk bf16 [4096][2048] + vt bf16 [2][1024][2048] (V^T)
// MODE 2: out_bf16 = gelu_tanh(acc + bias)
// ---------------------------------------------------------------------------
template <int MODE>
__global__ void __launch_bounds__(256) gemm_sb(
    const unsigned short* __restrict__ A, const unsigned short* __restrict__ B,
    int K, int N, unsigned short* __restrict__ outb,
    const float* __restrict__ bias, unsigned short* __restrict__ vt) {
  __shared__ unsigned short lA[128 * 64];
  __shared__ unsigned short lB[128 * 64];
  const int t = threadIdx.x, lane = t & 63;
  const int w = t >> 6, wm = w >> 1, wn = w & 1;
  const int r16 = lane & 15, g = lane >> 4;
  const int m0 = blockIdx.x * 128, n0 = blockIdx.y * 128;

  const unsigned short* aSrc[4];
  const unsigned short* bSrc[4];
#pragma unroll
  for (int p = 0; p < 4; ++p) {
    const int ci = t + p * 256, m = ci >> 3, cs = ci & 7;
    aSrc[p] = A + (size_t)(m0 + m) * K + (cs ^ (m & 7)) * 8;
    bSrc[p] = B + (size_t)(n0 + m) * K + (cs ^ (m & 7)) * 8;
  }
  int aOff[4][2], bOff[4][2];
#pragma unroll
  for (int i = 0; i < 4; ++i)
#pragma unroll
    for (int ks = 0; ks < 2; ++ks) {
      const int m = wm * 64 + i * 16 + r16, kb = ks * 4 + g;
      aOff[i][ks] = ((m << 3) + (kb ^ (m & 7))) << 3;
      const int n = wn * 64 + i * 16 + r16;
      bOff[i][ks] = ((n << 3) + (kb ^ (n & 7))) << 3;
    }

  f32x4 acc[4][4] = {};
  const int nkt = K >> 6;
  for (int kt = 0; kt < nkt; ++kt) {
    if (kt) __syncthreads();   // all waves done reading previous tile
    const int off = kt * 64;
#pragma unroll
    for (int p = 0; p < 4; ++p) {
      GLDS(aSrc[p] + off, &lA[(t + p * 256) * 8]);
      GLDS(bSrc[p] + off, &lB[(t + p * 256) * 8]);
    }
    __syncthreads();           // compiler drains vmcnt(0): tile staged
#pragma unroll
    for (int ks = 0; ks < 2; ++ks) {
      bf16x8 af[4], bfr[4];
#pragma unroll
      for (int i = 0; i < 4; ++i) {
        af[i]  = *(const bf16x8*)&lA[aOff[i][ks]];
        bfr[i] = *(const bf16x8*)&lB[bOff[i][ks]];
      }
      __builtin_amdgcn_s_setprio(1);
#pragma unroll
      for (int i = 0; i < 4; ++i)
#pragma unroll
        for (int j = 0; j < 4; ++j)
          acc[i][j] = __builtin_amdgcn_mfma_f32_16x16x32_bf16(
              af[i], bfr[j], acc[i][j], 0, 0, 0);
      __builtin_amdgcn_s_setprio(0);
    }
  }

  float bj[4];
  if constexpr (MODE == 2) {
#pragma unroll
    for (int j = 0; j < 4; ++j) bj[j] = bias[n0 + wn * 64 + j * 16 + r16];
  }
#pragma unroll
  for (int i = 0; i < 4; ++i) {
    const int row0 = m0 + wm * 64 + i * 16 + g * 4;
#pragma unroll
    for (int j = 0; j < 4; ++j) {
      const int colb = n0 + wn * 64 + j * 16;
      const int col = colb + r16;
      if constexpr (MODE == 0) {
        if (colb < 2048) {
#pragma unroll
          for (int r = 0; r < 4; ++r)
            outb[(size_t)(row0 + r) * 2048 + col] = f2b(acc[i][j][r]);
        } else {
          const int b = row0 >> 11, s0 = row0 & 2047;
          us4 pk;
          pk.x = f2b(acc[i][j][0]); pk.y = f2b(acc[i][j][1]);
          pk.z = f2b(acc[i][j][2]); pk.w = f2b(acc[i][j][3]);
          *(us4*)&vt[((size_t)b * 1024 + (col - 2048)) * 2048 + s0] = pk;
        }
      } else {
#pragma unroll
        for (int r = 0; r < 4; ++r) {
          const float x = acc[i][j][r] + bj[j];
          const float u = x * (0.7978845608028654f + 0.03567740814f * x * x);
          const float e = __builtin_amdgcn_exp2f(u * 2.885390081777927f);
          const float th = 1.0f - 2.0f * __builtin_amdgcn_rcpf(e + 1.0f);
          outb[(size_t)(row0 + r) * N + col] = f2b(0.5f * x * (1.0f + th));
        }
      }
    }
  }
}

// ---------------------------------------------------------------------------
// GEMM: C[M,N] = A[M,K](bf16) * B^T, B stored [N,K]. BMx128 tile, 4 waves.
// 2-deep counted-vmcnt pipeline (round-6 version). N=1024 GEMMs (Wo, FFN-dn).
// MODE 1: out_f32 = acc + resid ; MODE 3: out_f32 = acc + bias + resid
// ---------------------------------------------------------------------------
template <int MODE, int BM>
__global__ void __launch_bounds__(256) gemm_bt(
    const unsigned short* __restrict__ A, const unsigned short* __restrict__ B,
    int K, int N,
    float* __restrict__ outf, const float* __restrict__ bias,
    const float* __restrict__ resid) {
  constexpr int WN = (BM == 128) ? 2 : 4;   // waves along N
  constexpr int NJ = 128 / (16 * WN);       // N-fragments per wave
  constexpr int ACH = BM / 32;              // A staging passes
  __shared__ unsigned short lA[2][BM * 64];
  __shared__ unsigned short lB[2][128 * 64];
  const int t = threadIdx.x, lane = t & 63;
  const int w = t >> 6, wm = w / WN, wn = w % WN;
  const int r16 = lane & 15, g = lane >> 4;
  const int m0 = blockIdx.x * BM, n0 = blockIdx.y * 128;

  const unsigned short* aSrc[ACH];
  const unsigned short* bSrc[4];
#pragma unroll
  for (int p = 0; p < ACH; ++p) {
    const int ci = t + p * 256, m = ci >> 3, cs = ci & 7;
    aSrc[p] = A + (size_t)(m0 + m) * K + (cs ^ (m & 7)) * 8;
  }
#pragma unroll
  for (int p = 0; p < 4; ++p) {
    const int ci = t + p * 256, m = ci >> 3, cs = ci & 7;
    bSrc[p] = B + (size_t)(n0 + m) * K + (cs ^ (m & 7)) * 8;
  }

  int aOff[4][2], bOff[NJ][2];
#pragma unroll
  for (int i = 0; i < 4; ++i)
#pragma unroll
    for (int ks = 0; ks < 2; ++ks) {
      const int m = wm * 64 + i * 16 + r16, kb = ks * 4 + g;
      aOff[i][ks] = ((m << 3) + (kb ^ (m & 7))) << 3;
    }
#pragma unroll
  for (int j = 0; j < NJ; ++j)
#pragma unroll
    for (int ks = 0; ks < 2; ++ks) {
      const int n = wn * (16 * NJ) + j * 16 + r16, kb = ks * 4 + g;
      bOff[j][ks] = ((n << 3) + (kb ^ (n & 7))) << 3;
    }

  auto stage = [&](int buf, int kt) {
    const int off = kt * 64;
#pragma unroll
    for (int p = 0; p < ACH; ++p)
      GLDS(aSrc[p] + off, &lA[buf][(t + p * 256) * 8]);
#pragma unroll
    for (int p = 0; p < 4; ++p)
      GLDS(bSrc[p] + off, &lB[buf][(t + p * 256) * 8]);
  };

  f32x4 acc[4][NJ] = {};
  const int nkt = K >> 6;
  stage(0, 0);
  for (int kt = 0; kt < nkt; ++kt) {
    const int cur = kt & 1;
    if (kt + 1 < nkt) {
      stage(cur ^ 1, kt + 1);  // 6 loads into buf[cur^1], left in flight
      if constexpr (ACH == 2)
        asm volatile("s_waitcnt vmcnt(6)" ::: "memory");  // buf[cur] landed
      else
        asm volatile("s_waitcnt vmcnt(8)" ::: "memory");
    } else {
      asm volatile("s_waitcnt vmcnt(0)" ::: "memory");
    }
    __builtin_amdgcn_s_barrier();          // all waves: buf[cur] staged
    __builtin_amdgcn_sched_barrier(0);     // no LDS reads hoisted above
    const unsigned short* bA = lA[cur];
    const unsigned short* bB = lB[cur];
#pragma unroll
    for (int ks = 0; ks < 2; ++ks) {
      bf16x8 af[4], bfr[NJ];
#pragma unroll
      for (int i = 0; i < 4; ++i) af[i] = *(const bf16x8*)&bA[aOff[i][ks]];
#pragma unroll
      for (int j = 0; j < NJ; ++j) bfr[j] = *(const bf16x8*)&bB[bOff[j][ks]];
      __builtin_amdgcn_s_setprio(1);
#pragma unroll
      for (int i = 0; i < 4; ++i)
#pragma unroll
        for (int j = 0; j < NJ; ++j)
          acc[i][j] = __builtin_amdgcn_mfma_f32_16x16x32_bf16(
              af[i], bfr[j], acc[i][j], 0, 0, 0);
      __builtin_amdgcn_s_setprio(0);
    }
    __builtin_amdgcn_sched_barrier(0);     // no next-iter GLDS hoisted above
    __builtin_amdgcn_s_barrier();          // all waves done reading buf[cur]
  }

  float bj[NJ];
  if constexpr (MODE == 3) {
#pragma unroll
    for (int j = 0; j < NJ; ++j)
      bj[j] = bias[n0 + wn * (16 * NJ) + j * 16 + r16];
  }
#pragma unroll
  for (int i = 0; i < 4; ++i) {
    const int row0 = m0 + wm * 64 + i * 16 + g * 4;
#pragma unroll
    for (int j = 0; j < NJ; ++j) {
      const int col = n0 + wn * (16 * NJ) + j * 16 + r16;
      if constexpr (MODE == 1) {
#pragma unroll
        for (int r = 0; r < 4; ++r) {
          const size_t idx = (size_t)(row0 + r) * N + col;
          outf[idx] = acc[i][j][r] + resid[idx];
        }
      } else {
#pragma unroll
        for (int r = 0; r < 4; ++r) {
          const size_t idx = (size_t)(row0 + r) * N + col;
          outf[idx] = acc[i][j][r] + bj[j] + resid[idx];
        }
      }
    }
  }
}

// ---------------------------------------------------------------------------
// Flash attention (causal), load-balanced: block j handles q-tiles j and 31-j
// (33 compute-steps/block, one shared K/V staging pass). Grid (16,16,2),
// 4 waves, KVBLK=64 (best measured config).
// T5 setprio, T13 defer-max (THR=44 raw), cvt_pk packing, XOR-swizzled lP.
// ---------------------------------------------------------------------------
__global__ void __launch_bounds__(256) attn_kernel(
    const unsigned short* __restrict__ qk, const unsigned short* __restrict__ vt,
    unsigned short* __restrict__ obuf) {
  const int j = blockIdx.x, h = blockIdx.y, bb = blockIdx.z;
  const int t = threadIdx.x, lane = t & 63, w = t >> 6;
  const int r16 = lane & 15, g = lane >> 4;
  __shared__ unsigned short lK[2][64 * 64];
  __shared__ unsigned short lV[2][64 * 64];
  __shared__ unsigned short lP[4][16 * 64];

  const int qtA = j, qtB = 31 - j;   // qtA <= qtB
  const int ktmax = qtB;
  const int qrowA = qtA * 64 + w * 16 + r16;
  const int qrowB = qtB * 64 + w * 16 + r16;
  const float CE = 0.18033688011112042f;  // (1/8) * log2(e)

  bf16x8 qfA[2], qfB[2];
  {
    const unsigned short* qa = qk + (size_t)(bb * 2048 + qrowA) * 2048 + h * 64;
    qfA[0] = *(const bf16x8*)(qa + g * 8);
    qfA[1] = *(const bf16x8*)(qa + 32 + g * 8);
    const unsigned short* qb = qk + (size_t)(bb * 2048 + qrowB) * 2048 + h * 64;
    qfB[0] = *(const bf16x8*)(qb + g * 8);
    qfB[1] = *(const bf16x8*)(qb + 32 + g * 8);
  }

  f32x4 accA[4] = {}, accB[4] = {};
  float mA = -3.0e38f, lA_ = 0.0f, mB = -3.0e38f, lB_ = 0.0f;

  auto stage = [&](int buf, int kt) {
    const int k0 = kt * 64;
#pragma unroll
    for (int p = 0; p < 2; ++p) {
      const int ci = t + p * 256;
      const int r = ci >> 3, cs = ci & 7;
      const int cb = cs ^ (r & 7);
      GLDS(qk + (size_t)(bb * 2048 + k0 + r) * 2048 + 1024 + h * 64 + cb * 8,
           &lK[buf][ci * 8]);
      GLDS(vt + ((size_t)bb * 1024 + h * 64 + r) * 2048 + k0 + cb * 8,
           &lV[buf][ci * 8]);
    }
  };

  const int pswz = (r16 & 7) << 3;  // lP XOR swizzle (8-elem granules)

  auto flash_step = [&](const bf16x8* qf, f32x4* accO, float& mrun,
                        float& lrun, int qrow, bool diag, int k0, int cur) {
    f32x4 s[4] = {};
    __builtin_amdgcn_s_setprio(1);
#pragma unroll
    for (int ks = 0; ks < 2; ++ks)
#pragma unroll
      for (int mt = 0; mt < 4; ++mt) {
        const int r = mt * 16 + r16, db = ks * 4 + g;
        const bf16x8 kf =
            *(const bf16x8*)&lK[cur][((r << 3) + (db ^ (r & 7))) << 3];
        s[mt] = __builtin_amdgcn_mfma_f32_16x16x32_bf16(kf, qf[ks], s[mt],
                                                        0, 0, 0);
      }
    __builtin_amdgcn_s_setprio(0);
    if (diag) {
#pragma unroll
      for (int mt = 0; mt < 4; ++mt)
#pragma unroll
        for (int r = 0; r < 4; ++r)
          if (k0 + mt * 16 + g * 4 + r > qrow) s[mt][r] = -3.0e38f;
    }
    float tmax = -3.0e38f;
#pragma unroll
    for (int mt = 0; mt < 4; ++mt)
#pragma unroll
      for (int r = 0; r < 4; ++r) tmax = fmaxf(tmax, s[mt][r]);
    tmax = fmaxf(tmax, __shfl_xor(tmax, 16));
    tmax = fmaxf(tmax, __shfl_xor(tmax, 32));
    // T13 defer-max: only rescale when the running max grew materially
    if (!__all(tmax <= mrun + 44.0f)) {
      const float mnew = fmaxf(mrun, tmax);
      const float fac = __builtin_amdgcn_exp2f((mrun - mnew) * CE);
      lrun *= fac;
      float fr[4];
#pragma unroll
      for (int r = 0; r < 4; ++r) fr[r] = __shfl(fac, g * 4 + r);
#pragma unroll
      for (int nb = 0; nb < 4; ++nb)
#pragma unroll
        for (int r = 0; r < 4; ++r) accO[nb][r] *= fr[r];
      mrun = mnew;
    }
    float pv[4][4];
    float tsum = 0.0f;
#pragma unroll
    for (int mt = 0; mt < 4; ++mt)
#pragma unroll
      for (int r = 0; r < 4; ++r) {
        pv[mt][r] = __builtin_amdgcn_exp2f((s[mt][r] - mrun) * CE);
        tsum += pv[mt][r];
      }
    tsum += __shfl_xor(tsum, 16);
    tsum += __shfl_xor(tsum, 32);
    lrun += tsum;
    // write P^T (per-wave region, XOR-swizzled, cvt_pk packed)
#pragma unroll
    for (int mt = 0; mt < 4; ++mt) {
      u32x2 pk;
      pk.x = cvt_pk_bf16(pv[mt][0], pv[mt][1]);
      pk.y = cvt_pk_bf16(pv[mt][2], pv[mt][3]);
      *(u32x2*)&lP[w][r16 * 64 + ((mt * 16 + g * 4) ^ pswz)] = pk;
    }
    __builtin_amdgcn_s_setprio(1);
#pragma unroll
    for (int ks = 0; ks < 2; ++ks) {
      const bf16x8 pa =
          *(const bf16x8*)&lP[w][r16 * 64 + ((ks * 32 + g * 8) ^ pswz)];
#pragma unroll
      for (int nb = 0; nb < 4; ++nb) {
        const int d = nb * 16 + r16, kb = ks * 4 + g;
        const bf16x8 vf =
            *(const bf16x8*)&lV[cur][((d << 3) + (kb ^ (d & 7))) << 3];
        accO[nb] = __builtin_amdgcn_mfma_f32_16x16x32_bf16(pa, vf, accO[nb],
                                                           0, 0, 0);
      }
    }
    __builtin_amdgcn_s_setprio(0);
  };

  stage(0, 0);
  __syncthreads();
  int cur = 0;
  for (int kt = 0; kt <= ktmax; ++kt) {
    if (kt < ktmax) stage(cur ^ 1, kt + 1);
    flash_step(qfB, accB, mB, lB_, qrowB, kt == qtB, kt * 64, cur);
    if (kt <= qtA)
      flash_step(qfA, accA, mA, lA_, qrowA, kt == qtA, kt * 64, cur);
    __syncthreads();  // drains vmcnt: staged kt+1 complete + lK/lV[cur] free
    cur ^= 1;
  }

  auto epilogue = [&](const f32x4* accO, float lrun, int q0) {
    const float li = 1.0f / lrun;
    float lr_[4];
#pragma unroll
    for (int r = 0; r < 4; ++r) lr_[r] = __shfl(li, g * 4 + r);
#pragma unroll
    for (int nb = 0; nb < 4; ++nb)
#pragma unroll
      for (int r = 0; r < 4; ++r) {
        const int row = bb * 2048 + q0 + w * 16 + g * 4 + r;
        const int col = h * 64 + nb * 16 + r16;
        obuf[(size_t)row * 1024 + col] = f2b(accO[nb][r] * lr_[r]);
      }
  };
  epilogue(accA, lA_, qtA * 64);
  epilogue(accB, lB_, qtB * 64);
}

// ---------------------------------------------------------------------------
extern "C" void kernel_launch(void* const* d_in, const int* in_sizes, int n_in,
                              void* d_out, int out_size, void* d_ws,
                              size_t ws_size, hipStream_t stream) {
  const float* hs   = (const float*)d_in[0];
  const float* Wq   = (const float*)d_in[1];
  const float* Wk   = (const float*)d_in[2];
  const float* Wv   = (const float*)d_in[3];
  const float* Wo   = (const float*)d_in[4];
  const float* W1   = (const float*)d_in[5];
  const float* b1   = (const float*)d_in[6];
  const float* W2   = (const float*)d_in[7];
  const float* b2   = (const float*)d_in[8];
  const float* ln1s = (const float*)d_in[9];
  const float* ln1b = (const float*)d_in[10];
  const float* ln2s = (const float*)d_in[11];
  const float* ln2b = (const float*)d_in[12];
  float* out = (float*)d_out;

  char* ws = (char*)d_ws;
  unsigned short* wqkvT = (unsigned short*)(ws + 0);          //  6 MB [3072][1024]
  unsigned short* woT   = (unsigned short*)(ws + 6291456);    //  2 MB [1024][1024]
  unsigned short* w1T   = (unsigned short*)(ws + 8388608);    //  8 MB [4096][1024]
  unsigned short* w2T   = (unsigned short*)(ws + 16777216);   //  8 MB [1024][4096]
  float*          hid   = (float*)(ws + 25165824);            // 16 MB [4096][1024]
  unsigned short* xb    = (unsigned short*)(ws + 41943040);   //  8 MB [4096][1024]
  char*           big   = ws + 50331648;                      // 32 MB region
  unsigned short* qkb   = (unsigned short*)(big);             // 16 MB [4096][2048]
  unsigned short* vtb   = (unsigned short*)(big + 16777216);  //  8 MB [2][1024][2048]
  unsigned short* ob    = (unsigned short*)(big + 25165824);  //  8 MB [4096][1024]
  unsigned short* h1    = (unsigned short*)(big);             // 32 MB (reuse) [4096][4096]

  // fused: LN1 + all 6 weight transposes
  prep_kernel<<<16384, 256, 0, stream>>>(hs, ln1s, ln1b, xb,
                                         Wq, Wk, Wv, Wo, W1, W2,
                                         wqkvT, woT, w1T, w2T);
  // QKV projection (single-buffer 128^2, 3 blocks/CU; V written transposed)
  gemm_sb<0><<<dim3(32, 24), 256, 0, stream>>>(xb, wqkvT, 1024, 3072,
                                               qkb, nullptr, vtb);
  // attention (paired q-tiles, KVBLK=64 + micro-opts)
  attn_kernel<<<dim3(16, 16, 2), 256, 0, stream>>>(qkb, vtb, ob);
  // output projection + residual (BM=64, 2-deep counted-vmcnt)
  gemm_bt<1, 64><<<dim3(64, 8), 256, 0, stream>>>(ob, woT, 1024, 1024,
                                                  hid, nullptr, hs);
  // LN2
  ln_kernel<<<4096, 256, 0, stream>>>(hid, ln2s, ln2b, xb);
  // FFN up + GELU (tanh approx), single-buffer 128^2, 4 blocks/CU
  gemm_sb<2><<<dim3(32, 32), 256, 0, stream>>>(xb, w1T, 1024, 4096,
                                               h1, b1, nullptr);
  // FFN down + bias + residual -> out (BM=64, 2-deep counted-vmcnt)
  gemm_bt<3, 64><<<dim3(64, 8), 256, 0, stream>>>(h1, w2T, 4096, 1024,
                                                  out, b2, hid);
}

// Round 12
// 224.457 us; speedup vs baseline: 1.1124x; 1.0229x over previous
//
#include <hip/hip_runtime.h>
#include <math.h>

using bf16x8 = __attribute__((ext_vector_type(8))) short;
using f32x4  = __attribute__((ext_vector_type(4))) float;

struct __align__(8) us4 { unsigned short x, y, z, w; };
struct __align__(8) u32x2 { unsigned int x, y; };

__device__ __forceinline__ unsigned short f2b(float f) {
  union { float f; unsigned u; } v; v.f = f;
  unsigned r = v.u + 0x7FFFu + ((v.u >> 16) & 1u);
  return (unsigned short)(r >> 16);
}
__device__ __forceinline__ unsigned int cvt_pk_bf16(float lo, float hi) {
  unsigned int d;
  asm("v_cvt_pk_bf16_f32 %0, %1, %2" : "=v"(d) : "v"(lo), "v"(hi));
  return d;
}

#define GLDS(g, l) __builtin_amdgcn_global_load_lds(                        \
    (const __attribute__((address_space(1))) void*)(g),                    \
    (__attribute__((address_space(3))) void*)(l), 16, 0, 0)

// ---------------------------------------------------------------------------
// Fused prep: LN1 (blocks 0..4095) + all 6 weight transposes (fp32->bf16,
// [K][N] -> [N][K]) in one dispatch (measured ~-15us vs separate dispatches).
// ---------------------------------------------------------------------------
__global__ void __launch_bounds__(256) prep_kernel(
    const float* __restrict__ hs, const float* __restrict__ ln1s,
    const float* __restrict__ ln1b, unsigned short* __restrict__ xb,
    const float* __restrict__ Wq, const float* __restrict__ Wk,
    const float* __restrict__ Wv, const float* __restrict__ Wo,
    const float* __restrict__ W1, const float* __restrict__ W2,
    unsigned short* __restrict__ wqkvT, unsigned short* __restrict__ woT,
    unsigned short* __restrict__ w1T, unsigned short* __restrict__ w2T) {
  const int id = blockIdx.x;
  const int t = threadIdx.x;
  __shared__ float tile[32][33];
  __shared__ float red[8];

  if (id < 4096) {  // ---- LN1 row ----
    const int row = id;
    const float4 v = ((const float4*)(hs + (size_t)row * 1024))[t];
    float s  = v.x + v.y + v.z + v.w;
    float s2 = v.x * v.x + v.y * v.y + v.z * v.z + v.w * v.w;
#pragma unroll
    for (int off = 32; off; off >>= 1) {
      s  += __shfl_xor(s,  off);
      s2 += __shfl_xor(s2, off);
    }
    const int w = t >> 6, lane = t & 63;
    if (!lane) { red[w] = s; red[4 + w] = s2; }
    __syncthreads();
    s  = red[0] + red[1] + red[2] + red[3];
    s2 = red[4] + red[5] + red[6] + red[7];
    const float mean = s * (1.0f / 1024.0f);
    const float var  = s2 * (1.0f / 1024.0f) - mean * mean;
    const float rstd = rsqrtf(var + 1e-5f);
    const float4 sc = ((const float4*)ln1s)[t];
    const float4 sh = ((const float4*)ln1b)[t];
    us4 o;
    o.x = f2b((v.x - mean) * rstd * sc.x + sh.x);
    o.y = f2b((v.y - mean) * rstd * sc.y + sh.y);
    o.z = f2b((v.z - mean) * rstd * sc.z + sh.z);
    o.w = f2b((v.w - mean) * rstd * sc.w + sh.w);
    ((us4*)(xb + (size_t)row * 1024))[t] = o;
    return;
  }

  // ---- weight transpose tile ----
  const float* src; unsigned short* dst; int K, N, n0, k0;
  if (id < 8192) {            // Wq/Wk/Wv/Wo: 1024x1024, 32x32 grids
    const int which = (id - 4096) >> 10, local = (id - 4096) & 1023;
    src = (which == 0) ? Wq : (which == 1) ? Wk : (which == 2) ? Wv : Wo;
    dst = (which == 3) ? woT : wqkvT + (size_t)which * 1048576;
    K = 1024; N = 1024;
    n0 = (local & 31) * 32; k0 = (local >> 5) * 32;
  } else if (id < 12288) {    // W1: K=1024, N=4096, grid (128,32)
    const int local = id - 8192;
    src = W1; dst = w1T; K = 1024; N = 4096;
    n0 = (local & 127) * 32; k0 = (local >> 7) * 32;
  } else {                    // W2: K=4096, N=1024, grid (32,128)
    const int local = id - 12288;
    src = W2; dst = w2T; K = 4096; N = 1024;
    n0 = (local & 31) * 32; k0 = (local >> 5) * 32;
  }
  const int tx = t & 31, ty = t >> 5;  // 32 x 8
#pragma unroll
  for (int i = 0; i < 32; i += 8)
    tile[ty + i][tx] = src[(size_t)(k0 + ty + i) * N + n0 + tx];
  __syncthreads();
#pragma unroll
  for (int i = 0; i < 32; i += 8)
    dst[(size_t)(n0 + ty + i) * K + k0 + tx] = f2b(tile[tx][ty + i]);
}

// ---------------------------------------------------------------------------
// LayerNorm over last dim (1024), fp32 in -> bf16 out (LN2)
// ---------------------------------------------------------------------------
__global__ void __launch_bounds__(256) ln_kernel(
    const float* __restrict__ in, const float* __restrict__ scale,
    const float* __restrict__ shift, unsigned short* __restrict__ out) {
  const int row = blockIdx.x, t = threadIdx.x;
  const float4 v = ((const float4*)(in + (size_t)row * 1024))[t];
  float s  = v.x + v.y + v.z + v.w;
  float s2 = v.x * v.x + v.y * v.y + v.z * v.z + v.w * v.w;
#pragma unroll
  for (int off = 32; off; off >>= 1) {
    s  += __shfl_xor(s,  off);
    s2 += __shfl_xor(s2, off);
  }
  __shared__ float red[8];
  const int w = t >> 6, lane = t & 63;
  if (!lane) { red[w] = s; red[4 + w] = s2; }
  __syncthreads();
  s  = red[0] + red[1] + red[2] + red[3];
  s2 = red[4] + red[5] + red[6] + red[7];
  const float mean = s * (1.0f / 1024.0f);
  const float var  = s2 * (1.0f / 1024.0f) - mean * mean;
  const float rstd = rsqrtf(var + 1e-5f);
  const float4 sc = ((const float4*)scale)[t];
  const float4 sh = ((const float4*)shift)[t];
  us4 o;
  o.x = f2b((v.x - mean) * rstd * sc.x + sh.x);
  o.y = f2b((v.y - mean) * rstd * sc.y + sh.y);
  o.z = f2b((v.z - mean) * rstd * sc.z + sh.z);
  o.w = f2b((v.w - mean) * rstd * sc.w + sh.w);
  ((us4*)(out + (size_t)row * 1024))[t] = o;
}

// ---------------------------------------------------------------------------
// 256x256 GEMM, 8-phase m201-style schedule. 8 waves (2M x 4N), BK=64,
// 4 quadrant-phases per K-tile, each: {ds_read subtile | stage ONE half-tile
// (2 GLDS) | counted vmcnt | barrier | lgkmcnt(0) | setprio+16 MFMA | barrier}.
// Row-interleaved fragment maps (A row = i*32+wm*16, B row = j*64+wn*16) so
// LDS row-half regions align with phase read-sets:
//   B-h0 read only in q0, B-h1 in q1, A-h0 in q0/q1 (wait: i0-3 rows 0..127,
//   read q0 only), A-h1 (i4-7) in q2. Regions freed -> staged one phase later.
// Stage stream per tile T: q0->A-h1(T+1), q1->B-h0(T+2), q2->A-h0(T+2),
// q3->B-h1(T+2). Steady-state waits vmcnt(10)/(8); never 0 until final tile.
// MODE 0: qkv split -> qk bf16 [4096][2048] + vt bf16 [2][1024][2048] (V^T)
// MODE 2: out_bf16 = gelu_tanh(acc + bias)
// ---------------------------------------------------------------------------
template <int MODE>
__global__ void __launch_bounds__(512, 2) gemm8p(
    const unsigned short* __restrict__ A, const unsigned short* __restrict__ B,
    int K, int N, unsigned short* __restrict__ outb,
    const float* __restrict__ bias, unsigned short* __restrict__ vt) {
  __shared__ unsigned short lA[2][256 * 64];
  __shared__ unsigned short lB[2][256 * 64];
  const int t = threadIdx.x, lane = t & 63;
  const int w = t >> 6, wm = w >> 2, wn = w & 3;
  const int r16 = lane & 15, g = lane >> 4;
  const int m0 = blockIdx.x * 256, n0 = blockIdx.y * 256;

  // stage sources: thread covers (row = ci>>3, phys chunk = ci&7), ci=t+p*512
  // semantic kb = cs ^ (row&7) applied to the GLOBAL column (LDS stays linear)
  const unsigned short* aS[2];
  const unsigned short* bS[2];
  int ldst[2];
#pragma unroll
  for (int p = 0; p < 2; ++p) {
    const int ci = t + p * 512, r = ci >> 3, cs = ci & 7;
    aS[p] = A + (size_t)(m0 + r) * K + (cs ^ (r & 7)) * 8;
    bS[p] = B + (size_t)(n0 + r) * K + (cs ^ (r & 7)) * 8;
    ldst[p] = ci * 8;
  }
  const size_t hstep = (size_t)128 * K;  // +128 rows ((r+128)&7 == r&7)

  auto stageA = [&](int buf, int kt, int half) {
    const size_t off = (size_t)kt * 64 + (half ? hstep : 0);
    const int dof = half ? 8192 : 0;
#pragma unroll
    for (int p = 0; p < 2; ++p) GLDS(aS[p] + off, &lA[buf][dof + ldst[p]]);
  };
  auto stageB = [&](int buf, int kt, int half) {
    const size_t off = (size_t)kt * 64 + (half ? hstep : 0);
    const int dof = half ? 8192 : 0;
#pragma unroll
    for (int p = 0; p < 2; ++p) GLDS(bS[p] + off, &lB[buf][dof + ldst[p]]);
  };

  // fragment LDS element-offsets (row-interleaved maps)
  int aOff[8][2], bOff[4][2];
#pragma unroll
  for (int i = 0; i < 8; ++i)
#pragma unroll
    for (int ks = 0; ks < 2; ++ks) {
      const int row = i * 32 + wm * 16 + r16, kb = ks * 4 + g;
      aOff[i][ks] = ((row << 3) + (kb ^ (row & 7))) << 3;
    }
#pragma unroll
  for (int j = 0; j < 4; ++j)
#pragma unroll
    for (int ks = 0; ks < 2; ++ks) {
      const int row = j * 64 + wn * 16 + r16, kb = ks * 4 + g;
      bOff[j][ks] = ((row << 3) + (kb ^ (row & 7))) << 3;
    }

  auto vwait = [](int n) {
    if (n >= 10)     asm volatile("s_waitcnt vmcnt(10)" ::: "memory");
    else if (n >= 8) asm volatile("s_waitcnt vmcnt(8)" ::: "memory");
    else if (n >= 4) asm volatile("s_waitcnt vmcnt(4)" ::: "memory");
    else if (n >= 2) asm volatile("s_waitcnt vmcnt(2)" ::: "memory");
    else             asm volatile("s_waitcnt vmcnt(0)" ::: "memory");
  };

  const int nkt = K >> 6;  // >= 3 for all uses
  // prologue: A-h0(0),B-h0(0),B-h1(0),A-h1(0),A-h0(1),B-h0(1),B-h1(1)
  stageA(0, 0, 0); stageB(0, 0, 0); stageB(0, 0, 1); stageA(0, 0, 1);
  stageA(1, 1, 0); stageB(1, 1, 0); stageB(1, 1, 1);
  asm volatile("s_waitcnt vmcnt(10)" ::: "memory");  // first 2 stages landed
  __builtin_amdgcn_s_barrier();

  f32x4 acc[8][4] = {};
  bf16x8 af[4][2], b01[2][2], b23[2][2];
  for (int kt = 0; kt < nkt; ++kt) {
    const int cur = kt & 1, nxt = cur ^ 1;
    const unsigned short* bA = lA[cur];
    const unsigned short* bB = lB[cur];
    // ---- q0: read A i0-3 (8) + B j0-1 (4); stage A-h1(kt+1) ----
#pragma unroll
    for (int i = 0; i < 4; ++i) {
      af[i][0] = *(const bf16x8*)&bA[aOff[i][0]];
      af[i][1] = *(const bf16x8*)&bA[aOff[i][1]];
    }
#pragma unroll
    for (int j = 0; j < 2; ++j) {
      b01[j][0] = *(const bf16x8*)&bB[bOff[j][0]];
      b01[j][1] = *(const bf16x8*)&bB[bOff[j][1]];
    }
    if (kt + 1 < nkt) stageA(nxt, kt + 1, 1);
    asm volatile("s_waitcnt lgkmcnt(8)" ::: "memory");
    vwait(kt == nkt - 1 ? 2 : 10);          // validates q1's B-h1(kt)
    __builtin_amdgcn_s_barrier();
    asm volatile("s_waitcnt lgkmcnt(0)" ::: "memory");
    __builtin_amdgcn_sched_barrier(0);
    __builtin_amdgcn_s_setprio(1);
#pragma unroll
    for (int i = 0; i < 4; ++i)
#pragma unroll
      for (int j = 0; j < 2; ++j) {
        acc[i][j] = __builtin_amdgcn_mfma_f32_16x16x32_bf16(
            af[i][0], b01[j][0], acc[i][j], 0, 0, 0);
        acc[i][j] = __builtin_amdgcn_mfma_f32_16x16x32_bf16(
            af[i][1], b01[j][1], acc[i][j], 0, 0, 0);
      }
    __builtin_amdgcn_s_setprio(0);
    __builtin_amdgcn_s_barrier();
    // ---- q1: read B j2-3 (4); stage B-h0(kt+2) ----
#pragma unroll
    for (int j = 0; j < 2; ++j) {
      b23[j][0] = *(const bf16x8*)&bB[bOff[2 + j][0]];
      b23[j][1] = *(const bf16x8*)&bB[bOff[2 + j][1]];
    }
    if (kt + 2 < nkt) stageB(cur, kt + 2, 0);
    vwait(kt == nkt - 1 ? 0 : (kt == nkt - 2 ? 8 : 10));  // q2's A-h1(kt)
    __builtin_amdgcn_s_barrier();
    asm volatile("s_waitcnt lgkmcnt(0)" ::: "memory");
    __builtin_amdgcn_sched_barrier(0);
    __builtin_amdgcn_s_setprio(1);
#pragma unroll
    for (int i = 0; i < 4; ++i)
#pragma unroll
      for (int j = 0; j < 2; ++j) {
        acc[i][2 + j] = __builtin_amdgcn_mfma_f32_16x16x32_bf16(
            af[i][0], b23[j][0], acc[i][2 + j], 0, 0, 0);
        acc[i][2 + j] = __builtin_amdgcn_mfma_f32_16x16x32_bf16(
            af[i][1], b23[j][1], acc[i][2 + j], 0, 0, 0);
      }
    __builtin_amdgcn_s_setprio(0);
    __builtin_amdgcn_s_barrier();
    // ---- q2: read A i4-7 (8); stage A-h0(kt+2) ----
#pragma unroll
    for (int i = 0; i < 4; ++i) {
      af[i][0] = *(const bf16x8*)&bA[aOff[4 + i][0]];
      af[i][1] = *(const bf16x8*)&bA[aOff[4 + i][1]];
    }
    if (kt + 2 < nkt) stageA(cur, kt + 2, 0);
    __builtin_amdgcn_s_barrier();
    asm volatile("s_waitcnt lgkmcnt(0)" ::: "memory");
    __builtin_amdgcn_sched_barrier(0);
    __builtin_amdgcn_s_setprio(1);
#pragma unroll
    for (int i = 0; i < 4; ++i)
#pragma unroll
      for (int j = 0; j < 2; ++j) {
        acc[4 + i][j] = __builtin_amdgcn_mfma_f32_16x16x32_bf16(
            af[i][0], b01[j][0], acc[4 + i][j], 0, 0, 0);
        acc[4 + i][j] = __builtin_amdgcn_mfma_f32_16x16x32_bf16(
            af[i][1], b01[j][1], acc[4 + i][j], 0, 0, 0);
      }
    __builtin_amdgcn_s_setprio(0);
    __builtin_amdgcn_s_barrier();
    // ---- q3: 0 reads; stage B-h1(kt+2); vmcnt validates next q0 ----
    if (kt + 2 < nkt) stageB(cur, kt + 2, 1);
    __builtin_amdgcn_s_barrier();
    __builtin_amdgcn_s_setprio(1);
#pragma unroll
    for (int i = 0; i < 4; ++i)
#pragma unroll
      for (int j = 0; j < 2; ++j) {
        acc[4 + i][2 + j] = __builtin_amdgcn_mfma_f32_16x16x32_bf16(
            af[i][0], b23[j][0], acc[4 + i][2 + j], 0, 0, 0);
        acc[4 + i][2 + j] = __builtin_amdgcn_mfma_f32_16x16x32_bf16(
            af[i][1], b23[j][1], acc[4 + i][2 + j], 0, 0, 0);
      }
    __builtin_amdgcn_s_setprio(0);
    if (kt < nkt - 1) vwait(kt == nkt - 2 ? 4 : 10);
    __builtin_amdgcn_s_barrier();
  }

  // epilogue: C/D layout col = lane&15, row = (lane>>4)*4 + reg
  float bj[4];
  if constexpr (MODE == 2) {
#pragma unroll
    for (int j = 0; j < 4; ++j)
      bj[j] = bias[n0 + j * 64 + wn * 16 + r16];
  }
#pragma unroll
  for (int i = 0; i < 8; ++i) {
    const int row0 = m0 + i * 32 + wm * 16 + g * 4;
#pragma unroll
    for (int j = 0; j < 4; ++j) {
      const int colb = n0 + j * 64 + wn * 16;
      const int col = colb + r16;
      if constexpr (MODE == 0) {
        if (colb < 2048) {
#pragma unroll
          for (int r = 0; r < 4; ++r)
            outb[(size_t)(row0 + r) * 2048 + col] = f2b(acc[i][j][r]);
        } else {
          const int b = row0 >> 11, s0 = row0 & 2047;
          us4 pk;
          pk.x = f2b(acc[i][j][0]); pk.y = f2b(acc[i][j][1]);
          pk.z = f2b(acc[i][j][2]); pk.w = f2b(acc[i][j][3]);
          *(us4*)&vt[((size_t)b * 1024 + (col - 2048)) * 2048 + s0] = pk;
        }
      } else {
#pragma unroll
        for (int r = 0; r < 4; ++r) {
          const float x = acc[i][j][r] + bj[j];
          const float u = x * (0.7978845608028654f + 0.03567740814f * x * x);
          const float e = __builtin_amdgcn_exp2f(u * 2.885390081777927f);
          const float th = 1.0f - 2.0f * __builtin_amdgcn_rcpf(e + 1.0f);
          outb[(size_t)(row0 + r) * N + col] = f2b(0.5f * x * (1.0f + th));
        }
      }
    }
  }
}

// ---------------------------------------------------------------------------
// GEMM: C[M,N] = A[M,K](bf16) * B^T, B stored [N,K]. BMx128 tile, 4 waves.
// 2-deep counted-vmcnt pipeline (round-6 version). N=1024 GEMMs (Wo, FFN-dn).
// MODE 1: out_f32 = acc + resid ; MODE 3: out_f32 = acc + bias + resid
// ---------------------------------------------------------------------------
template <int MODE, int BM>
__global__ void __launch_bounds__(256) gemm_bt(
    const unsigned short* __restrict__ A, const unsigned short* __restrict__ B,
    int K, int N,
    float* __restrict__ outf, const float* __restrict__ bias,
    const float* __restrict__ resid) {
  constexpr int WN = (BM == 128) ? 2 : 4;   // waves along N
  constexpr int NJ = 128 / (16 * WN);       // N-fragments per wave
  constexpr int ACH = BM / 32;              // A staging passes
  __shared__ unsigned short lA[2][BM * 64];
  __shared__ unsigned short lB[2][128 * 64];
  const int t = threadIdx.x, lane = t & 63;
  const int w = t >> 6, wm = w / WN, wn = w % WN;
  const int r16 = lane & 15, g = lane >> 4;
  const int m0 = blockIdx.x * BM, n0 = blockIdx.y * 128;

  const unsigned short* aSrc[ACH];
  const unsigned short* bSrc[4];
#pragma unroll
  for (int p = 0; p < ACH; ++p) {
    const int ci = t + p * 256, m = ci >> 3, cs = ci & 7;
    aSrc[p] = A + (size_t)(m0 + m) * K + (cs ^ (m & 7)) * 8;
  }
#pragma unroll
  for (int p = 0; p < 4; ++p) {
    const int ci = t + p * 256, m = ci >> 3, cs = ci & 7;
    bSrc[p] = B + (size_t)(n0 + m) * K + (cs ^ (m & 7)) * 8;
  }

  int aOff[4][2], bOff[NJ][2];
#pragma unroll
  for (int i = 0; i < 4; ++i)
#pragma unroll
    for (int ks = 0; ks < 2; ++ks) {
      const int m = wm * 64 + i * 16 + r16, kb = ks * 4 + g;
      aOff[i][ks] = ((m << 3) + (kb ^ (m & 7))) << 3;
    }
#pragma unroll
  for (int j = 0; j < NJ; ++j)
#pragma unroll
    for (int ks = 0; ks < 2; ++ks) {
      const int n = wn * (16 * NJ) + j * 16 + r16, kb = ks * 4 + g;
      bOff[j][ks] = ((n << 3) + (kb ^ (n & 7))) << 3;
    }

  auto stage = [&](int buf, int kt) {
    const int off = kt * 64;
#pragma unroll
    for (int p = 0; p < ACH; ++p)
      GLDS(aSrc[p] + off, &lA[buf][(t + p * 256) * 8]);
#pragma unroll
    for (int p = 0; p < 4; ++p)
      GLDS(bSrc[p] + off, &lB[buf][(t + p * 256) * 8]);
  };

  f32x4 acc[4][NJ] = {};
  const int nkt = K >> 6;
  stage(0, 0);
  for (int kt = 0; kt < nkt; ++kt) {
    const int cur = kt & 1;
    if (kt + 1 < nkt) {
      stage(cur ^ 1, kt + 1);  // 6 loads into buf[cur^1], left in flight
      if constexpr (ACH == 2)
        asm volatile("s_waitcnt vmcnt(6)" ::: "memory");  // buf[cur] landed
      else
        asm volatile("s_waitcnt vmcnt(8)" ::: "memory");
    } else {
      asm volatile("s_waitcnt vmcnt(0)" ::: "memory");
    }
    __builtin_amdgcn_s_barrier();          // all waves: buf[cur] staged
    __builtin_amdgcn_sched_barrier(0);     // no LDS reads hoisted above
    const unsigned short* bA = lA[cur];
    const unsigned short* bB = lB[cur];
#pragma unroll
    for (int ks = 0; ks < 2; ++ks) {
      bf16x8 af[4], bfr[NJ];
#pragma unroll
      for (int i = 0; i < 4; ++i) af[i] = *(const bf16x8*)&bA[aOff[i][ks]];
#pragma unroll
      for (int j = 0; j < NJ; ++j) bfr[j] = *(const bf16x8*)&bB[bOff[j][ks]];
      __builtin_amdgcn_s_setprio(1);
#pragma unroll
      for (int i = 0; i < 4; ++i)
#pragma unroll
        for (int j = 0; j < NJ; ++j)
          acc[i][j] = __builtin_amdgcn_mfma_f32_16x16x32_bf16(
              af[i], bfr[j], acc[i][j], 0, 0, 0);
      __builtin_amdgcn_s_setprio(0);
    }
    __builtin_amdgcn_sched_barrier(0);     // no next-iter GLDS hoisted above
    __builtin_amdgcn_s_barrier();          // all waves done reading buf[cur]
  }

  float bj[NJ];
  if constexpr (MODE == 3) {
#pragma unroll
    for (int j = 0; j < NJ; ++j)
      bj[j] = bias[n0 + wn * (16 * NJ) + j * 16 + r16];
  }
#pragma unroll
  for (int i = 0; i < 4; ++i) {
    const int row0 = m0 + wm * 64 + i * 16 + g * 4;
#pragma unroll
    for (int j = 0; j < NJ; ++j) {
      const int col = n0 + wn * (16 * NJ) + j * 16 + r16;
      if constexpr (MODE == 1) {
#pragma unroll
        for (int r = 0; r < 4; ++r) {
          const size_t idx = (size_t)(row0 + r) * N + col;
          outf[idx] = acc[i][j][r] + resid[idx];
        }
      } else {
#pragma unroll
        for (int r = 0; r < 4; ++r) {
          const size_t idx = (size_t)(row0 + r) * N + col;
          outf[idx] = acc[i][j][r] + bj[j] + resid[idx];
        }
      }
    }
  }
}

// ---------------------------------------------------------------------------
// Flash attention (causal), load-balanced: block j handles q-tiles j and 31-j
// (33 compute-steps/block, one shared K/V staging pass). Grid (16,16,2),
// 4 waves, KVBLK=64 (best measured config).
// T5 setprio, T13 defer-max (THR=44 raw), cvt_pk packing, XOR-swizzled lP.
// ---------------------------------------------------------------------------
__global__ void __launch_bounds__(256) attn_kernel(
    const unsigned short* __restrict__ qk, const unsigned short* __restrict__ vt,
    unsigned short* __restrict__ obuf) {
  const int j = blockIdx.x, h = blockIdx.y, bb = blockIdx.z;
  const int t = threadIdx.x, lane = t & 63, w = t >> 6;
  const int r16 = lane & 15, g = lane >> 4;
  __shared__ unsigned short lK[2][64 * 64];
  __shared__ unsigned short lV[2][64 * 64];
  __shared__ unsigned short lP[4][16 * 64];

  const int qtA = j, qtB = 31 - j;   // qtA <= qtB
  const int ktmax = qtB;
  const int qrowA = qtA * 64 + w * 16 + r16;
  const int qrowB = qtB * 64 + w * 16 + r16;
  const float CE = 0.18033688011112042f;  // (1/8) * log2(e)

  bf16x8 qfA[2], qfB[2];
  {
    const unsigned short* qa = qk + (size_t)(bb * 2048 + qrowA) * 2048 + h * 64;
    qfA[0] = *(const bf16x8*)(qa + g * 8);
    qfA[1] = *(const bf16x8*)(qa + 32 + g * 8);
    const unsigned short* qb = qk + (size_t)(bb * 2048 + qrowB) * 2048 + h * 64;
    qfB[0] = *(const bf16x8*)(qb + g * 8);
    qfB[1] = *(const bf16x8*)(qb + 32 + g * 8);
  }

  f32x4 accA[4] = {}, accB[4] = {};
  float mA = -3.0e38f, lA_ = 0.0f, mB = -3.0e38f, lB_ = 0.0f;

  auto stage = [&](int buf, int kt) {
    const int k0 = kt * 64;
#pragma unroll
    for (int p = 0; p < 2; ++p) {
      const int ci = t + p * 256;
      const int r = ci >> 3, cs = ci & 7;
      const int cb = cs ^ (r & 7);
      GLDS(qk + (size_t)(bb * 2048 + k0 + r) * 2048 + 1024 + h * 64 + cb * 8,
           &lK[buf][ci * 8]);
      GLDS(vt + ((size_t)bb * 1024 + h * 64 + r) * 2048 + k0 + cb * 8,
           &lV[buf][ci * 8]);
    }
  };

  const int pswz = (r16 & 7) << 3;  // lP XOR swizzle (8-elem granules)

  auto flash_step = [&](const bf16x8* qf, f32x4* accO, float& mrun,
                        float& lrun, int qrow, bool diag, int k0, int cur) {
    f32x4 s[4] = {};
    __builtin_amdgcn_s_setprio(1);
#pragma unroll
    for (int ks = 0; ks < 2; ++ks)
#pragma unroll
      for (int mt = 0; mt < 4; ++mt) {
        const int r = mt * 16 + r16, db = ks * 4 + g;
        const bf16x8 kf =
            *(const bf16x8*)&lK[cur][((r << 3) + (db ^ (r & 7))) << 3];
        s[mt] = __builtin_amdgcn_mfma_f32_16x16x32_bf16(kf, qf[ks], s[mt],
                                                        0, 0, 0);
      }
    __builtin_amdgcn_s_setprio(0);
    if (diag) {
#pragma unroll
      for (int mt = 0; mt < 4; ++mt)
#pragma unroll
        for (int r = 0; r < 4; ++r)
          if (k0 + mt * 16 + g * 4 + r > qrow) s[mt][r] = -3.0e38f;
    }
    float tmax = -3.0e38f;
#pragma unroll
    for (int mt = 0; mt < 4; ++mt)
#pragma unroll
      for (int r = 0; r < 4; ++r) tmax = fmaxf(tmax, s[mt][r]);
    tmax = fmaxf(tmax, __shfl_xor(tmax, 16));
    tmax = fmaxf(tmax, __shfl_xor(tmax, 32));
    // T13 defer-max: only rescale when the running max grew materially
    if (!__all(tmax <= mrun + 44.0f)) {
      const float mnew = fmaxf(mrun, tmax);
      const float fac = __builtin_amdgcn_exp2f((mrun - mnew) * CE);
      lrun *= fac;
      float fr[4];
#pragma unroll
      for (int r = 0; r < 4; ++r) fr[r] = __shfl(fac, g * 4 + r);
#pragma unroll
      for (int nb = 0; nb < 4; ++nb)
#pragma unroll
        for (int r = 0; r < 4; ++r) accO[nb][r] *= fr[r];
      mrun = mnew;
    }
    float pv[4][4];
    float tsum = 0.0f;
#pragma unroll
    for (int mt = 0; mt < 4; ++mt)
#pragma unroll
      for (int r = 0; r < 4; ++r) {
        pv[mt][r] = __builtin_amdgcn_exp2f((s[mt][r] - mrun) * CE);
        tsum += pv[mt][r];
      }
    tsum += __shfl_xor(tsum, 16);
    tsum += __shfl_xor(tsum, 32);
    lrun += tsum;
    // write P^T (per-wave region, XOR-swizzled, cvt_pk packed)
#pragma unroll
    for (int mt = 0; mt < 4; ++mt) {
      u32x2 pk;
      pk.x = cvt_pk_bf16(pv[mt][0], pv[mt][1]);
      pk.y = cvt_pk_bf16(pv[mt][2], pv[mt][3]);
      *(u32x2*)&lP[w][r16 * 64 + ((mt * 16 + g * 4) ^ pswz)] = pk;
    }
    __builtin_amdgcn_s_setprio(1);
#pragma unroll
    for (int ks = 0; ks < 2; ++ks) {
      const bf16x8 pa =
          *(const bf16x8*)&lP[w][r16 * 64 + ((ks * 32 + g * 8) ^ pswz)];
#pragma unroll
      for (int nb = 0; nb < 4; ++nb) {
        const int d = nb * 16 + r16, kb = ks * 4 + g;
        const bf16x8 vf =
            *(const bf16x8*)&lV[cur][((d << 3) + (kb ^ (d & 7))) << 3];
        accO[nb] = __builtin_amdgcn_mfma_f32_16x16x32_bf16(pa, vf, accO[nb],
                                                           0, 0, 0);
      }
    }
    __builtin_amdgcn_s_setprio(0);
  };

  stage(0, 0);
  __syncthreads();
  int cur = 0;
  for (int kt = 0; kt <= ktmax; ++kt) {
    if (kt < ktmax) stage(cur ^ 1, kt + 1);
    flash_step(qfB, accB, mB, lB_, qrowB, kt == qtB, kt * 64, cur);
    if (kt <= qtA)
      flash_step(qfA, accA, mA, lA_, qrowA, kt == qtA, kt * 64, cur);
    __syncthreads();  // drains vmcnt: staged kt+1 complete + lK/lV[cur] free
    cur ^= 1;
  }

  auto epilogue = [&](const f32x4* accO, float lrun, int q0) {
    const float li = 1.0f / lrun;
    float lr_[4];
#pragma unroll
    for (int r = 0; r < 4; ++r) lr_[r] = __shfl(li, g * 4 + r);
#pragma unroll
    for (int nb = 0; nb < 4; ++nb)
#pragma unroll
      for (int r = 0; r < 4; ++r) {
        const int row = bb * 2048 + q0 + w * 16 + g * 4 + r;
        const int col = h * 64 + nb * 16 + r16;
        obuf[(size_t)row * 1024 + col] = f2b(accO[nb][r] * lr_[r]);
      }
  };
  epilogue(accA, lA_, qtA * 64);
  epilogue(accB, lB_, qtB * 64);
}

// ---------------------------------------------------------------------------
extern "C" void kernel_launch(void* const* d_in, const int* in_sizes, int n_in,
                              void* d_out, int out_size, void* d_ws,
                              size_t ws_size, hipStream_t stream) {
  const float* hs   = (const float*)d_in[0];
  const float* Wq   = (const float*)d_in[1];
  const float* Wk   = (const float*)d_in[2];
  const float* Wv   = (const float*)d_in[3];
  const float* Wo   = (const float*)d_in[4];
  const float* W1   = (const float*)d_in[5];
  const float* b1   = (const float*)d_in[6];
  const float* W2   = (const float*)d_in[7];
  const float* b2   = (const float*)d_in[8];
  const float* ln1s = (const float*)d_in[9];
  const float* ln1b = (const float*)d_in[10];
  const float* ln2s = (const float*)d_in[11];
  const float* ln2b = (const float*)d_in[12];
  float* out = (float*)d_out;

  char* ws = (char*)d_ws;
  unsigned short* wqkvT = (unsigned short*)(ws + 0);          //  6 MB [3072][1024]
  unsigned short* woT   = (unsigned short*)(ws + 6291456);    //  2 MB [1024][1024]
  unsigned short* w1T   = (unsigned short*)(ws + 8388608);    //  8 MB [4096][1024]
  unsigned short* w2T   = (unsigned short*)(ws + 16777216);   //  8 MB [1024][4096]
  float*          hid   = (float*)(ws + 25165824);            // 16 MB [4096][1024]
  unsigned short* xb    = (unsigned short*)(ws + 41943040);   //  8 MB [4096][1024]
  char*           big   = ws + 50331648;                      // 32 MB region
  unsigned short* qkb   = (unsigned short*)(big);             // 16 MB [4096][2048]
  unsigned short* vtb   = (unsigned short*)(big + 16777216);  //  8 MB [2][1024][2048]
  unsigned short* ob    = (unsigned short*)(big + 25165824);  //  8 MB [4096][1024]
  unsigned short* h1    = (unsigned short*)(big);             // 32 MB (reuse) [4096][4096]

  // fused: LN1 + all 6 weight transposes
  prep_kernel<<<16384, 256, 0, stream>>>(hs, ln1s, ln1b, xb,
                                         Wq, Wk, Wv, Wo, W1, W2,
                                         wqkvT, woT, w1T, w2T);
  // QKV projection (256^2 8-phase pipeline; V written transposed)
  gemm8p<0><<<dim3(16, 12), 512, 0, stream>>>(xb, wqkvT, 1024, 3072,
                                              qkb, nullptr, vtb);
  // attention (paired q-tiles, KVBLK=64 + micro-opts)
  attn_kernel<<<dim3(16, 16, 2), 256, 0, stream>>>(qkb, vtb, ob);
  // output projection + residual (BM=64, 2-deep counted-vmcnt)
  gemm_bt<1, 64><<<dim3(64, 8), 256, 0, stream>>>(ob, woT, 1024, 1024,
                                                  hid, nullptr, hs);
  // LN2
  ln_kernel<<<4096, 256, 0, stream>>>(hid, ln2s, ln2b, xb);
  // FFN up + GELU (tanh approx), 256^2 8-phase pipeline
  gemm8p<2><<<dim3(16, 16), 512, 0, stream>>>(xb, w1T, 1024, 4096,
                                              h1, b1, nullptr);
  // FFN down + bias + residual -> out (BM=64, 2-deep counted-vmcnt)
  gemm_bt<3, 64><<<dim3(64, 8), 256, 0, stream>>>(h1, w2T, 4096, 1024,
                                                  out, b2, hid);
}

// Round 13
// 218.430 us; speedup vs baseline: 1.1430x; 1.0276x over previous
//
#include <hip/hip_runtime.h>
#include <math.h>

using bf16x8 = __attribute__((ext_vector_type(8))) short;
using f32x4  = __attribute__((ext_vector_type(4))) float;

struct __align__(8) us4 { unsigned short x, y, z, w; };
struct __align__(8) u32x2 { unsigned int x, y; };

__device__ __forceinline__ unsigned short f2b(float f) {
  union { float f; unsigned u; } v; v.f = f;
  unsigned r = v.u + 0x7FFFu + ((v.u >> 16) & 1u);
  return (unsigned short)(r >> 16);
}
__device__ __forceinline__ unsigned int cvt_pk_bf16(float lo, float hi) {
  unsigned int d;
  asm("v_cvt_pk_bf16_f32 %0, %1, %2" : "=v"(d) : "v"(lo), "v"(hi));
  return d;
}

#define GLDS(g, l) __builtin_amdgcn_global_load_lds(                        \
    (const __attribute__((address_space(1))) void*)(g),                    \
    (__attribute__((address_space(3))) void*)(l), 16, 0, 0)

// ---------------------------------------------------------------------------
// Fused prep: LN1 (blocks 0..4095) + all 6 weight transposes (fp32->bf16,
// [K][N] -> [N][K]) in one dispatch (measured ~-15us vs separate dispatches).
// ---------------------------------------------------------------------------
__global__ void __launch_bounds__(256) prep_kernel(
    const float* __restrict__ hs, const float* __restrict__ ln1s,
    const float* __restrict__ ln1b, unsigned short* __restrict__ xb,
    const float* __restrict__ Wq, const float* __restrict__ Wk,
    const float* __restrict__ Wv, const float* __restrict__ Wo,
    const float* __restrict__ W1, const float* __restrict__ W2,
    unsigned short* __restrict__ wqkvT, unsigned short* __restrict__ woT,
    unsigned short* __restrict__ w1T, unsigned short* __restrict__ w2T) {
  const int id = blockIdx.x;
  const int t = threadIdx.x;
  __shared__ float tile[32][33];
  __shared__ float red[8];

  if (id < 4096) {  // ---- LN1 row ----
    const int row = id;
    const float4 v = ((const float4*)(hs + (size_t)row * 1024))[t];
    float s  = v.x + v.y + v.z + v.w;
    float s2 = v.x * v.x + v.y * v.y + v.z * v.z + v.w * v.w;
#pragma unroll
    for (int off = 32; off; off >>= 1) {
      s  += __shfl_xor(s,  off);
      s2 += __shfl_xor(s2, off);
    }
    const int w = t >> 6, lane = t & 63;
    if (!lane) { red[w] = s; red[4 + w] = s2; }
    __syncthreads();
    s  = red[0] + red[1] + red[2] + red[3];
    s2 = red[4] + red[5] + red[6] + red[7];
    const float mean = s * (1.0f / 1024.0f);
    const float var  = s2 * (1.0f / 1024.0f) - mean * mean;
    const float rstd = rsqrtf(var + 1e-5f);
    const float4 sc = ((const float4*)ln1s)[t];
    const float4 sh = ((const float4*)ln1b)[t];
    us4 o;
    o.x = f2b((v.x - mean) * rstd * sc.x + sh.x);
    o.y = f2b((v.y - mean) * rstd * sc.y + sh.y);
    o.z = f2b((v.z - mean) * rstd * sc.z + sh.z);
    o.w = f2b((v.w - mean) * rstd * sc.w + sh.w);
    ((us4*)(xb + (size_t)row * 1024))[t] = o;
    return;
  }

  // ---- weight transpose tile ----
  const float* src; unsigned short* dst; int K, N, n0, k0;
  if (id < 8192) {            // Wq/Wk/Wv/Wo: 1024x1024, 32x32 grids
    const int which = (id - 4096) >> 10, local = (id - 4096) & 1023;
    src = (which == 0) ? Wq : (which == 1) ? Wk : (which == 2) ? Wv : Wo;
    dst = (which == 3) ? woT : wqkvT + (size_t)which * 1048576;
    K = 1024; N = 1024;
    n0 = (local & 31) * 32; k0 = (local >> 5) * 32;
  } else if (id < 12288) {    // W1: K=1024, N=4096, grid (128,32)
    const int local = id - 8192;
    src = W1; dst = w1T; K = 1024; N = 4096;
    n0 = (local & 127) * 32; k0 = (local >> 7) * 32;
  } else {                    // W2: K=4096, N=1024, grid (32,128)
    const int local = id - 12288;
    src = W2; dst = w2T; K = 4096; N = 1024;
    n0 = (local & 31) * 32; k0 = (local >> 5) * 32;
  }
  const int tx = t & 31, ty = t >> 5;  // 32 x 8
#pragma unroll
  for (int i = 0; i < 32; i += 8)
    tile[ty + i][tx] = src[(size_t)(k0 + ty + i) * N + n0 + tx];
  __syncthreads();
#pragma unroll
  for (int i = 0; i < 32; i += 8)
    dst[(size_t)(n0 + ty + i) * K + k0 + tx] = f2b(tile[tx][ty + i]);
}

// ---------------------------------------------------------------------------
// LayerNorm over last dim (1024), fp32 in -> bf16 out (LN2)
// ---------------------------------------------------------------------------
__global__ void __launch_bounds__(256) ln_kernel(
    const float* __restrict__ in, const float* __restrict__ scale,
    const float* __restrict__ shift, unsigned short* __restrict__ out) {
  const int row = blockIdx.x, t = threadIdx.x;
  const float4 v = ((const float4*)(in + (size_t)row * 1024))[t];
  float s  = v.x + v.y + v.z + v.w;
  float s2 = v.x * v.x + v.y * v.y + v.z * v.z + v.w * v.w;
#pragma unroll
  for (int off = 32; off; off >>= 1) {
    s  += __shfl_xor(s,  off);
    s2 += __shfl_xor(s2, off);
  }
  __shared__ float red[8];
  const int w = t >> 6, lane = t & 63;
  if (!lane) { red[w] = s; red[4 + w] = s2; }
  __syncthreads();
  s  = red[0] + red[1] + red[2] + red[3];
  s2 = red[4] + red[5] + red[6] + red[7];
  const float mean = s * (1.0f / 1024.0f);
  const float var  = s2 * (1.0f / 1024.0f) - mean * mean;
  const float rstd = rsqrtf(var + 1e-5f);
  const float4 sc = ((const float4*)scale)[t];
  const float4 sh = ((const float4*)shift)[t];
  us4 o;
  o.x = f2b((v.x - mean) * rstd * sc.x + sh.x);
  o.y = f2b((v.y - mean) * rstd * sc.y + sh.y);
  o.z = f2b((v.z - mean) * rstd * sc.z + sh.z);
  o.w = f2b((v.w - mean) * rstd * sc.w + sh.w);
  ((us4*)(out + (size_t)row * 1024))[t] = o;
}

// ---------------------------------------------------------------------------
// 256x256 GEMM, 8-phase m201-style schedule (round-12 version — measured
// win). 8 waves (2M x 4N), BK=64, 4 quadrant-phases per K-tile with
// phase-distributed half-tile staging and counted vmcnt (never 0 mid-loop).
// MODE 0: qkv split -> qk bf16 [4096][2048] + vt bf16 [2][1024][2048] (V^T)
// MODE 2: out_bf16 = gelu_tanh(acc + bias)
// ---------------------------------------------------------------------------
template <int MODE>
__global__ void __launch_bounds__(512, 2) gemm8p(
    const unsigned short* __restrict__ A, const unsigned short* __restrict__ B,
    int K, int N, unsigned short* __restrict__ outb,
    const float* __restrict__ bias, unsigned short* __restrict__ vt) {
  __shared__ unsigned short lA[2][256 * 64];
  __shared__ unsigned short lB[2][256 * 64];
  const int t = threadIdx.x, lane = t & 63;
  const int w = t >> 6, wm = w >> 2, wn = w & 3;
  const int r16 = lane & 15, g = lane >> 4;
  const int m0 = blockIdx.x * 256, n0 = blockIdx.y * 256;

  const unsigned short* aS[2];
  const unsigned short* bS[2];
  int ldst[2];
#pragma unroll
  for (int p = 0; p < 2; ++p) {
    const int ci = t + p * 512, r = ci >> 3, cs = ci & 7;
    aS[p] = A + (size_t)(m0 + r) * K + (cs ^ (r & 7)) * 8;
    bS[p] = B + (size_t)(n0 + r) * K + (cs ^ (r & 7)) * 8;
    ldst[p] = ci * 8;
  }
  const size_t hstep = (size_t)128 * K;

  auto stageA = [&](int buf, int kt, int half) {
    const size_t off = (size_t)kt * 64 + (half ? hstep : 0);
    const int dof = half ? 8192 : 0;
#pragma unroll
    for (int p = 0; p < 2; ++p) GLDS(aS[p] + off, &lA[buf][dof + ldst[p]]);
  };
  auto stageB = [&](int buf, int kt, int half) {
    const size_t off = (size_t)kt * 64 + (half ? hstep : 0);
    const int dof = half ? 8192 : 0;
#pragma unroll
    for (int p = 0; p < 2; ++p) GLDS(bS[p] + off, &lB[buf][dof + ldst[p]]);
  };

  int aOff[8][2], bOff[4][2];
#pragma unroll
  for (int i = 0; i < 8; ++i)
#pragma unroll
    for (int ks = 0; ks < 2; ++ks) {
      const int row = i * 32 + wm * 16 + r16, kb = ks * 4 + g;
      aOff[i][ks] = ((row << 3) + (kb ^ (row & 7))) << 3;
    }
#pragma unroll
  for (int j = 0; j < 4; ++j)
#pragma unroll
    for (int ks = 0; ks < 2; ++ks) {
      const int row = j * 64 + wn * 16 + r16, kb = ks * 4 + g;
      bOff[j][ks] = ((row << 3) + (kb ^ (row & 7))) << 3;
    }

  auto vwait = [](int n) {
    if (n >= 10)     asm volatile("s_waitcnt vmcnt(10)" ::: "memory");
    else if (n >= 8) asm volatile("s_waitcnt vmcnt(8)" ::: "memory");
    else if (n >= 4) asm volatile("s_waitcnt vmcnt(4)" ::: "memory");
    else if (n >= 2) asm volatile("s_waitcnt vmcnt(2)" ::: "memory");
    else             asm volatile("s_waitcnt vmcnt(0)" ::: "memory");
  };

  const int nkt = K >> 6;
  stageA(0, 0, 0); stageB(0, 0, 0); stageB(0, 0, 1); stageA(0, 0, 1);
  stageA(1, 1, 0); stageB(1, 1, 0); stageB(1, 1, 1);
  asm volatile("s_waitcnt vmcnt(10)" ::: "memory");
  __builtin_amdgcn_s_barrier();

  f32x4 acc[8][4] = {};
  bf16x8 af[4][2], b01[2][2], b23[2][2];
  for (int kt = 0; kt < nkt; ++kt) {
    const int cur = kt & 1, nxt = cur ^ 1;
    const unsigned short* bA = lA[cur];
    const unsigned short* bB = lB[cur];
    // ---- q0 ----
#pragma unroll
    for (int i = 0; i < 4; ++i) {
      af[i][0] = *(const bf16x8*)&bA[aOff[i][0]];
      af[i][1] = *(const bf16x8*)&bA[aOff[i][1]];
    }
#pragma unroll
    for (int j = 0; j < 2; ++j) {
      b01[j][0] = *(const bf16x8*)&bB[bOff[j][0]];
      b01[j][1] = *(const bf16x8*)&bB[bOff[j][1]];
    }
    if (kt + 1 < nkt) stageA(nxt, kt + 1, 1);
    asm volatile("s_waitcnt lgkmcnt(8)" ::: "memory");
    vwait(kt == nkt - 1 ? 2 : 10);
    __builtin_amdgcn_s_barrier();
    asm volatile("s_waitcnt lgkmcnt(0)" ::: "memory");
    __builtin_amdgcn_sched_barrier(0);
    __builtin_amdgcn_s_setprio(1);
#pragma unroll
    for (int i = 0; i < 4; ++i)
#pragma unroll
      for (int j = 0; j < 2; ++j) {
        acc[i][j] = __builtin_amdgcn_mfma_f32_16x16x32_bf16(
            af[i][0], b01[j][0], acc[i][j], 0, 0, 0);
        acc[i][j] = __builtin_amdgcn_mfma_f32_16x16x32_bf16(
            af[i][1], b01[j][1], acc[i][j], 0, 0, 0);
      }
    __builtin_amdgcn_s_setprio(0);
    __builtin_amdgcn_s_barrier();
    // ---- q1 ----
#pragma unroll
    for (int j = 0; j < 2; ++j) {
      b23[j][0] = *(const bf16x8*)&bB[bOff[2 + j][0]];
      b23[j][1] = *(const bf16x8*)&bB[bOff[2 + j][1]];
    }
    if (kt + 2 < nkt) stageB(cur, kt + 2, 0);
    vwait(kt == nkt - 1 ? 0 : (kt == nkt - 2 ? 8 : 10));
    __builtin_amdgcn_s_barrier();
    asm volatile("s_waitcnt lgkmcnt(0)" ::: "memory");
    __builtin_amdgcn_sched_barrier(0);
    __builtin_amdgcn_s_setprio(1);
#pragma unroll
    for (int i = 0; i < 4; ++i)
#pragma unroll
      for (int j = 0; j < 2; ++j) {
        acc[i][2 + j] = __builtin_amdgcn_mfma_f32_16x16x32_bf16(
            af[i][0], b23[j][0], acc[i][2 + j], 0, 0, 0);
        acc[i][2 + j] = __builtin_amdgcn_mfma_f32_16x16x32_bf16(
            af[i][1], b23[j][1], acc[i][2 + j], 0, 0, 0);
      }
    __builtin_amdgcn_s_setprio(0);
    __builtin_amdgcn_s_barrier();
    // ---- q2 ----
#pragma unroll
    for (int i = 0; i < 4; ++i) {
      af[i][0] = *(const bf16x8*)&bA[aOff[4 + i][0]];
      af[i][1] = *(const bf16x8*)&bA[aOff[4 + i][1]];
    }
    if (kt + 2 < nkt) stageA(cur, kt + 2, 0);
    __builtin_amdgcn_s_barrier();
    asm volatile("s_waitcnt lgkmcnt(0)" ::: "memory");
    __builtin_amdgcn_sched_barrier(0);
    __builtin_amdgcn_s_setprio(1);
#pragma unroll
    for (int i = 0; i < 4; ++i)
#pragma unroll
      for (int j = 0; j < 2; ++j) {
        acc[4 + i][j] = __builtin_amdgcn_mfma_f32_16x16x32_bf16(
            af[i][0], b01[j][0], acc[4 + i][j], 0, 0, 0);
        acc[4 + i][j] = __builtin_amdgcn_mfma_f32_16x16x32_bf16(
            af[i][1], b01[j][1], acc[4 + i][j], 0, 0, 0);
      }
    __builtin_amdgcn_s_setprio(0);
    __builtin_amdgcn_s_barrier();
    // ---- q3 ----
    if (kt + 2 < nkt) stageB(cur, kt + 2, 1);
    __builtin_amdgcn_s_barrier();
    __builtin_amdgcn_s_setprio(1);
#pragma unroll
    for (int i = 0; i < 4; ++i)
#pragma unroll
      for (int j = 0; j < 2; ++j) {
        acc[4 + i][2 + j] = __builtin_amdgcn_mfma_f32_16x16x32_bf16(
            af[i][0], b23[j][0], acc[4 + i][2 + j], 0, 0, 0);
        acc[4 + i][2 + j] = __builtin_amdgcn_mfma_f32_16x16x32_bf16(
            af[i][1], b23[j][1], acc[4 + i][2 + j], 0, 0, 0);
      }
    __builtin_amdgcn_s_setprio(0);
    if (kt < nkt - 1) vwait(kt == nkt - 2 ? 4 : 10);
    __builtin_amdgcn_s_barrier();
  }

  float bj[4];
  if constexpr (MODE == 2) {
#pragma unroll
    for (int j = 0; j < 4; ++j)
      bj[j] = bias[n0 + j * 64 + wn * 16 + r16];
  }
#pragma unroll
  for (int i = 0; i < 8; ++i) {
    const int row0 = m0 + i * 32 + wm * 16 + g * 4;
#pragma unroll
    for (int j = 0; j < 4; ++j) {
      const int colb = n0 + j * 64 + wn * 16;
      const int col = colb + r16;
      if constexpr (MODE == 0) {
        if (colb < 2048) {
#pragma unroll
          for (int r = 0; r < 4; ++r)
            outb[(size_t)(row0 + r) * 2048 + col] = f2b(acc[i][j][r]);
        } else {
          const int b = row0 >> 11, s0 = row0 & 2047;
          us4 pk;
          pk.x = f2b(acc[i][j][0]); pk.y = f2b(acc[i][j][1]);
          pk.z = f2b(acc[i][j][2]); pk.w = f2b(acc[i][j][3]);
          *(us4*)&vt[((size_t)b * 1024 + (col - 2048)) * 2048 + s0] = pk;
        }
      } else {
#pragma unroll
        for (int r = 0; r < 4; ++r) {
          const float x = acc[i][j][r] + bj[j];
          const float u = x * (0.7978845608028654f + 0.03567740814f * x * x);
          const float e = __builtin_amdgcn_exp2f(u * 2.885390081777927f);
          const float th = 1.0f - 2.0f * __builtin_amdgcn_rcpf(e + 1.0f);
          outb[(size_t)(row0 + r) * N + col] = f2b(0.5f * x * (1.0f + th));
        }
      }
    }
  }
}

// ---------------------------------------------------------------------------
// GEMM: C[M,N] = A[M,K](bf16) * B^T, B stored [N,K]. BM x BN tile, 4 waves,
// 2-deep counted-vmcnt pipeline. BN=64 -> grid doubles (1024 blocks =
// 4 blocks/CU, LDS 32KB) for the grid-capped N=1024 GEMMs (Wo, FFN-down):
// TLP hides the barrier drain (m97 evidence: same structure at 3/CU = 874 TF).
// MODE 1: out_f32 = acc + resid ; MODE 3: out_f32 = acc + bias + resid
// ---------------------------------------------------------------------------
template <int MODE, int BM, int BN>
__global__ void __launch_bounds__(256) gemm_bt(
    const unsigned short* __restrict__ A, const unsigned short* __restrict__ B,
    int K, int N,
    float* __restrict__ outf, const float* __restrict__ bias,
    const float* __restrict__ resid) {
  constexpr int WN = 4;                     // waves along N
  constexpr int NJ = BN / (16 * WN);        // N-fragments per wave
  constexpr int ACH = BM / 32;              // A staging passes
  constexpr int BCH = BN / 32;              // B staging passes
  constexpr int TOT = ACH + BCH;            // GLDS per tile
  __shared__ unsigned short lA[2][BM * 64];
  __shared__ unsigned short lB[2][BN * 64];
  const int t = threadIdx.x, lane = t & 63;
  const int w = t >> 6, wm = w / WN, wn = w % WN;
  const int r16 = lane & 15, g = lane >> 4;
  const int m0 = blockIdx.x * BM, n0 = blockIdx.y * BN;

  const unsigned short* aSrc[ACH];
  const unsigned short* bSrc[BCH];
#pragma unroll
  for (int p = 0; p < ACH; ++p) {
    const int ci = t + p * 256, m = ci >> 3, cs = ci & 7;
    aSrc[p] = A + (size_t)(m0 + m) * K + (cs ^ (m & 7)) * 8;
  }
#pragma unroll
  for (int p = 0; p < BCH; ++p) {
    const int ci = t + p * 256, m = ci >> 3, cs = ci & 7;
    bSrc[p] = B + (size_t)(n0 + m) * K + (cs ^ (m & 7)) * 8;
  }

  int aOff[4][2], bOff[NJ][2];
#pragma unroll
  for (int i = 0; i < 4; ++i)
#pragma unroll
    for (int ks = 0; ks < 2; ++ks) {
      const int m = wm * 64 + i * 16 + r16, kb = ks * 4 + g;
      aOff[i][ks] = ((m << 3) + (kb ^ (m & 7))) << 3;
    }
#pragma unroll
  for (int j = 0; j < NJ; ++j)
#pragma unroll
    for (int ks = 0; ks < 2; ++ks) {
      const int n = wn * (16 * NJ) + j * 16 + r16, kb = ks * 4 + g;
      bOff[j][ks] = ((n << 3) + (kb ^ (n & 7))) << 3;
    }

  auto stage = [&](int buf, int kt) {
    const int off = kt * 64;
#pragma unroll
    for (int p = 0; p < ACH; ++p)
      GLDS(aSrc[p] + off, &lA[buf][(t + p * 256) * 8]);
#pragma unroll
    for (int p = 0; p < BCH; ++p)
      GLDS(bSrc[p] + off, &lB[buf][(t + p * 256) * 8]);
  };

  f32x4 acc[4][NJ] = {};
  const int nkt = K >> 6;
  stage(0, 0);
  for (int kt = 0; kt < nkt; ++kt) {
    const int cur = kt & 1;
    if (kt + 1 < nkt) {
      stage(cur ^ 1, kt + 1);  // loads into buf[cur^1], left in flight
      if constexpr (TOT == 4)
        asm volatile("s_waitcnt vmcnt(4)" ::: "memory");
      else if constexpr (TOT == 6)
        asm volatile("s_waitcnt vmcnt(6)" ::: "memory");
      else
        asm volatile("s_waitcnt vmcnt(8)" ::: "memory");
    } else {
      asm volatile("s_waitcnt vmcnt(0)" ::: "memory");
    }
    __builtin_amdgcn_s_barrier();          // all waves: buf[cur] staged
    __builtin_amdgcn_sched_barrier(0);     // no LDS reads hoisted above
    const unsigned short* bA = lA[cur];
    const unsigned short* bB = lB[cur];
#pragma unroll
    for (int ks = 0; ks < 2; ++ks) {
      bf16x8 af[4], bfr[NJ];
#pragma unroll
      for (int i = 0; i < 4; ++i) af[i] = *(const bf16x8*)&bA[aOff[i][ks]];
#pragma unroll
      for (int j = 0; j < NJ; ++j) bfr[j] = *(const bf16x8*)&bB[bOff[j][ks]];
      __builtin_amdgcn_s_setprio(1);
#pragma unroll
      for (int i = 0; i < 4; ++i)
#pragma unroll
        for (int j = 0; j < NJ; ++j)
          acc[i][j] = __builtin_amdgcn_mfma_f32_16x16x32_bf16(
              af[i], bfr[j], acc[i][j], 0, 0, 0);
      __builtin_amdgcn_s_setprio(0);
    }
    __builtin_amdgcn_sched_barrier(0);     // no next-iter GLDS hoisted above
    __builtin_amdgcn_s_barrier();          // all waves done reading buf[cur]
  }

  float bj[NJ];
  if constexpr (MODE == 3) {
#pragma unroll
    for (int j = 0; j < NJ; ++j)
      bj[j] = bias[n0 + wn * (16 * NJ) + j * 16 + r16];
  }
#pragma unroll
  for (int i = 0; i < 4; ++i) {
    const int row0 = m0 + wm * 64 + i * 16 + g * 4;
#pragma unroll
    for (int j = 0; j < NJ; ++j) {
      const int col = n0 + wn * (16 * NJ) + j * 16 + r16;
      if constexpr (MODE == 1) {
#pragma unroll
        for (int r = 0; r < 4; ++r) {
          const size_t idx = (size_t)(row0 + r) * N + col;
          outf[idx] = acc[i][j][r] + resid[idx];
        }
      } else {
#pragma unroll
        for (int r = 0; r < 4; ++r) {
          const size_t idx = (size_t)(row0 + r) * N + col;
          outf[idx] = acc[i][j][r] + bj[j] + resid[idx];
        }
      }
    }
  }
}

// ---------------------------------------------------------------------------
// Flash attention (causal), load-balanced: block j handles q-tiles j and 31-j
// (33 compute-steps/block, one shared K/V staging pass). Grid (16,16,2),
// 4 waves, KVBLK=64 (best measured config).
// T5 setprio, T13 defer-max (THR=44 raw), cvt_pk packing, XOR-swizzled lP.
// ---------------------------------------------------------------------------
__global__ void __launch_bounds__(256) attn_kernel(
    const unsigned short* __restrict__ qk, const unsigned short* __restrict__ vt,
    unsigned short* __restrict__ obuf) {
  const int j = blockIdx.x, h = blockIdx.y, bb = blockIdx.z;
  const int t = threadIdx.x, lane = t & 63, w = t >> 6;
  const int r16 = lane & 15, g = lane >> 4;
  __shared__ unsigned short lK[2][64 * 64];
  __shared__ unsigned short lV[2][64 * 64];
  __shared__ unsigned short lP[4][16 * 64];

  const int qtA = j, qtB = 31 - j;   // qtA <= qtB
  const int ktmax = qtB;
  const int qrowA = qtA * 64 + w * 16 + r16;
  const int qrowB = qtB * 64 + w * 16 + r16;
  const float CE = 0.18033688011112042f;  // (1/8) * log2(e)

  bf16x8 qfA[2], qfB[2];
  {
    const unsigned short* qa = qk + (size_t)(bb * 2048 + qrowA) * 2048 + h * 64;
    qfA[0] = *(const bf16x8*)(qa + g * 8);
    qfA[1] = *(const bf16x8*)(qa + 32 + g * 8);
    const unsigned short* qb = qk + (size_t)(bb * 2048 + qrowB) * 2048 + h * 64;
    qfB[0] = *(const bf16x8*)(qb + g * 8);
    qfB[1] = *(const bf16x8*)(qb + 32 + g * 8);
  }

  f32x4 accA[4] = {}, accB[4] = {};
  float mA = -3.0e38f, lA_ = 0.0f, mB = -3.0e38f, lB_ = 0.0f;

  auto stage = [&](int buf, int kt) {
    const int k0 = kt * 64;
#pragma unroll
    for (int p = 0; p < 2; ++p) {
      const int ci = t + p * 256;
      const int r = ci >> 3, cs = ci & 7;
      const int cb = cs ^ (r & 7);
      GLDS(qk + (size_t)(bb * 2048 + k0 + r) * 2048 + 1024 + h * 64 + cb * 8,
           &lK[buf][ci * 8]);
      GLDS(vt + ((size_t)bb * 1024 + h * 64 + r) * 2048 + k0 + cb * 8,
           &lV[buf][ci * 8]);
    }
  };

  const int pswz = (r16 & 7) << 3;  // lP XOR swizzle (8-elem granules)

  auto flash_step = [&](const bf16x8* qf, f32x4* accO, float& mrun,
                        float& lrun, int qrow, bool diag, int k0, int cur) {
    f32x4 s[4] = {};
    __builtin_amdgcn_s_setprio(1);
#pragma unroll
    for (int ks = 0; ks < 2; ++ks)
#pragma unroll
      for (int mt = 0; mt < 4; ++mt) {
        const int r = mt * 16 + r16, db = ks * 4 + g;
        const bf16x8 kf =
            *(const bf16x8*)&lK[cur][((r << 3) + (db ^ (r & 7))) << 3];
        s[mt] = __builtin_amdgcn_mfma_f32_16x16x32_bf16(kf, qf[ks], s[mt],
                                                        0, 0, 0);
      }
    __builtin_amdgcn_s_setprio(0);
    if (diag) {
#pragma unroll
      for (int mt = 0; mt < 4; ++mt)
#pragma unroll
        for (int r = 0; r < 4; ++r)
          if (k0 + mt * 16 + g * 4 + r > qrow) s[mt][r] = -3.0e38f;
    }
    float tmax = -3.0e38f;
#pragma unroll
    for (int mt = 0; mt < 4; ++mt)
#pragma unroll
      for (int r = 0; r < 4; ++r) tmax = fmaxf(tmax, s[mt][r]);
    tmax = fmaxf(tmax, __shfl_xor(tmax, 16));
    tmax = fmaxf(tmax, __shfl_xor(tmax, 32));
    // T13 defer-max: only rescale when the running max grew materially
    if (!__all(tmax <= mrun + 44.0f)) {
      const float mnew = fmaxf(mrun, tmax);
      const float fac = __builtin_amdgcn_exp2f((mrun - mnew) * CE);
      lrun *= fac;
      float fr[4];
#pragma unroll
      for (int r = 0; r < 4; ++r) fr[r] = __shfl(fac, g * 4 + r);
#pragma unroll
      for (int nb = 0; nb < 4; ++nb)
#pragma unroll
        for (int r = 0; r < 4; ++r) accO[nb][r] *= fr[r];
      mrun = mnew;
    }
    float pv[4][4];
    float tsum = 0.0f;
#pragma unroll
    for (int mt = 0; mt < 4; ++mt)
#pragma unroll
      for (int r = 0; r < 4; ++r) {
        pv[mt][r] = __builtin_amdgcn_exp2f((s[mt][r] - mrun) * CE);
        tsum += pv[mt][r];
      }
    tsum += __shfl_xor(tsum, 16);
    tsum += __shfl_xor(tsum, 32);
    lrun += tsum;
    // write P^T (per-wave region, XOR-swizzled, cvt_pk packed)
#pragma unroll
    for (int mt = 0; mt < 4; ++mt) {
      u32x2 pk;
      pk.x = cvt_pk_bf16(pv[mt][0], pv[mt][1]);
      pk.y = cvt_pk_bf16(pv[mt][2], pv[mt][3]);
      *(u32x2*)&lP[w][r16 * 64 + ((mt * 16 + g * 4) ^ pswz)] = pk;
    }
    __builtin_amdgcn_s_setprio(1);
#pragma unroll
    for (int ks = 0; ks < 2; ++ks) {
      const bf16x8 pa =
          *(const bf16x8*)&lP[w][r16 * 64 + ((ks * 32 + g * 8) ^ pswz)];
#pragma unroll
      for (int nb = 0; nb < 4; ++nb) {
        const int d = nb * 16 + r16, kb = ks * 4 + g;
        const bf16x8 vf =
            *(const bf16x8*)&lV[cur][((d << 3) + (kb ^ (d & 7))) << 3];
        accO[nb] = __builtin_amdgcn_mfma_f32_16x16x32_bf16(pa, vf, accO[nb],
                                                           0, 0, 0);
      }
    }
    __builtin_amdgcn_s_setprio(0);
  };

  stage(0, 0);
  __syncthreads();
  int cur = 0;
  for (int kt = 0; kt <= ktmax; ++kt) {
    if (kt < ktmax) stage(cur ^ 1, kt + 1);
    flash_step(qfB, accB, mB, lB_, qrowB, kt == qtB, kt * 64, cur);
    if (kt <= qtA)
      flash_step(qfA, accA, mA, lA_, qrowA, kt == qtA, kt * 64, cur);
    __syncthreads();  // drains vmcnt: staged kt+1 complete + lK/lV[cur] free
    cur ^= 1;
  }

  auto epilogue = [&](const f32x4* accO, float lrun, int q0) {
    const float li = 1.0f / lrun;
    float lr_[4];
#pragma unroll
    for (int r = 0; r < 4; ++r) lr_[r] = __shfl(li, g * 4 + r);
#pragma unroll
    for (int nb = 0; nb < 4; ++nb)
#pragma unroll
      for (int r = 0; r < 4; ++r) {
        const int row = bb * 2048 + q0 + w * 16 + g * 4 + r;
        const int col = h * 64 + nb * 16 + r16;
        obuf[(size_t)row * 1024 + col] = f2b(accO[nb][r] * lr_[r]);
      }
  };
  epilogue(accA, lA_, qtA * 64);
  epilogue(accB, lB_, qtB * 64);
}

// ---------------------------------------------------------------------------
extern "C" void kernel_launch(void* const* d_in, const int* in_sizes, int n_in,
                              void* d_out, int out_size, void* d_ws,
                              size_t ws_size, hipStream_t stream) {
  const float* hs   = (const float*)d_in[0];
  const float* Wq   = (const float*)d_in[1];
  const float* Wk   = (const float*)d_in[2];
  const float* Wv   = (const float*)d_in[3];
  const float* Wo   = (const float*)d_in[4];
  const float* W1   = (const float*)d_in[5];
  const float* b1   = (const float*)d_in[6];
  const float* W2   = (const float*)d_in[7];
  const float* b2   = (const float*)d_in[8];
  const float* ln1s = (const float*)d_in[9];
  const float* ln1b = (const float*)d_in[10];
  const float* ln2s = (const float*)d_in[11];
  const float* ln2b = (const float*)d_in[12];
  float* out = (float*)d_out;

  char* ws = (char*)d_ws;
  unsigned short* wqkvT = (unsigned short*)(ws + 0);          //  6 MB [3072][1024]
  unsigned short* woT   = (unsigned short*)(ws + 6291456);    //  2 MB [1024][1024]
  unsigned short* w1T   = (unsigned short*)(ws + 8388608);    //  8 MB [4096][1024]
  unsigned short* w2T   = (unsigned short*)(ws + 16777216);   //  8 MB [1024][4096]
  float*          hid   = (float*)(ws + 25165824);            // 16 MB [4096][1024]
  unsigned short* xb    = (unsigned short*)(ws + 41943040);   //  8 MB [4096][1024]
  char*           big   = ws + 50331648;                      // 32 MB region
  unsigned short* qkb   = (unsigned short*)(big);             // 16 MB [4096][2048]
  unsigned short* vtb   = (unsigned short*)(big + 16777216);  //  8 MB [2][1024][2048]
  unsigned short* ob    = (unsigned short*)(big + 25165824);  //  8 MB [4096][1024]
  unsigned short* h1    = (unsigned short*)(big);             // 32 MB (reuse) [4096][4096]

  // fused: LN1 + all 6 weight transposes
  prep_kernel<<<16384, 256, 0, stream>>>(hs, ln1s, ln1b, xb,
                                         Wq, Wk, Wv, Wo, W1, W2,
                                         wqkvT, woT, w1T, w2T);
  // QKV projection (256^2 8-phase pipeline; V written transposed)
  gemm8p<0><<<dim3(16, 12), 512, 0, stream>>>(xb, wqkvT, 1024, 3072,
                                              qkb, nullptr, vtb);
  // attention (paired q-tiles, KVBLK=64 + micro-opts)
  attn_kernel<<<dim3(16, 16, 2), 256, 0, stream>>>(qkb, vtb, ob);
  // output projection + residual (BM=64 BN=64 -> 1024 blocks, 4/CU)
  gemm_bt<1, 64, 64><<<dim3(64, 16), 256, 0, stream>>>(ob, woT, 1024, 1024,
                                                       hid, nullptr, hs);
  // LN2
  ln_kernel<<<4096, 256, 0, stream>>>(hid, ln2s, ln2b, xb);
  // FFN up + GELU (tanh approx), 256^2 8-phase pipeline
  gemm8p<2><<<dim3(16, 16), 512, 0, stream>>>(xb, w1T, 1024, 4096,
                                              h1, b1, nullptr);
  // FFN down + bias + residual -> out (BM=64 BN=64 -> 1024 blocks, 4/CU)
  gemm_bt<3, 64, 64><<<dim3(64, 16), 256, 0, stream>>>(h1, w2T, 4096, 1024,
                                                       out, b2, hid);
}